// Round 8
// baseline (565.647 us; speedup 1.0000x reference)
//
#include <hip/hip_runtime.h>
#include <cstddef>
#include <cstdint>

#define NB 256
#define NS 20
#define NL 512
#define ND 128
#define NH 768
#define ROWE (NS*(ND+NH))   // 17920 floats per output row
#define TL 16               // l-rows per tile
#define NT 16               // tiles per block (l-range 256 per block)

typedef __attribute__((ext_vector_type(4))) float  f32x4;
typedef __attribute__((ext_vector_type(8))) short  bf16x8;
typedef __attribute__((ext_vector_type(4))) short  short4v;
typedef __attribute__((ext_vector_type(4))) unsigned short ushort4v;
typedef __attribute__((ext_vector_type(8))) unsigned short ushort8v;

#define MFMA16 __builtin_amdgcn_mfma_f32_16x16x32_bf16

__device__ __forceinline__ unsigned short bf16_rne(float v){
    unsigned u = __builtin_bit_cast(unsigned, v);
    u = (u + 0x7fffu + ((u>>16)&1u)) >> 16;
    return (unsigned short)u;
}
__device__ __forceinline__ float bf16f(unsigned short h){
    unsigned u = ((unsigned)h)<<16;
    return __builtin_bit_cast(float, u);
}

// ---------------------------------------------------------------------------
// K1: se = embs[skills[b]] -> out (concat left part);  q = se @ W -> bf16
// hi/lo arrays in ws. 256 blocks x 256 threads; wave w owns s in [5w,5w+5).
// ---------------------------------------------------------------------------
extern "C" __global__ __launch_bounds__(256)
void k1_q(const int* __restrict__ skills, const float* __restrict__ embs,
          const float* __restrict__ W,
          unsigned short* __restrict__ qhi, unsigned short* __restrict__ qlo,
          float* __restrict__ out)
{
    __shared__ float se[NS*ND];
    __shared__ int   sk[NS];
    const int b = blockIdx.x, t = threadIdx.x;
    if (t < NS) sk[t] = skills[b*NS + t];
    __syncthreads();
    for (int idx = t; idx < NS*ND; idx += 256) {
        const int s = idx >> 7, d = idx & (ND-1);
        const float v = embs[(size_t)sk[s]*ND + d];
        se[idx] = v;
        out[(size_t)b*ROWE + (size_t)s*(ND+NH) + d] = v;
    }
    __syncthreads();

    const int w = t >> 6, lane = t & 63;
    float acc[5][12];
    #pragma unroll
    for (int i = 0; i < 5; ++i)
        #pragma unroll
        for (int c = 0; c < 12; ++c) acc[i][c] = 0.f;

    const float* Wl = W + lane;
    for (int d4 = 0; d4 < ND/4; ++d4) {
        f32x4 sv[5];
        #pragma unroll
        for (int i = 0; i < 5; ++i)
            sv[i] = *(const f32x4*)&se[(5*w + i)*ND + 4*d4];
        #pragma unroll
        for (int r = 0; r < 4; ++r) {
            const float* wr = Wl + (size_t)(4*d4 + r)*NH;
            float wv[12];
            #pragma unroll
            for (int c = 0; c < 12; ++c) wv[c] = wr[64*c];
            #pragma unroll
            for (int i = 0; i < 5; ++i) {
                const float s_ = sv[i][r];
                #pragma unroll
                for (int c = 0; c < 12; ++c) acc[i][c] += s_*wv[c];
            }
        }
    }
    #pragma unroll
    for (int i = 0; i < 5; ++i)
        #pragma unroll
        for (int c = 0; c < 12; ++c) {
            const size_t idx = ((size_t)b*NS + 5*w + i)*NH + lane + 64*c;
            const float v = acc[i][c];
            const unsigned short hh = bf16_rne(v);
            qhi[idx] = hh;
            qlo[idx] = bf16_rne(v - bf16f(hh));
        }
}

// ---------------------------------------------------------------------------
// K2F: flash attention partial over an l-range of 256.  Grid (NB, 2); block
// (b, lh) handles l in [256*lh, 256*lh+256) as 16 tiles of TL=16 rows.
// 512 threads (8 waves), LDS 75.6 KB -> 2 blocks/CU: one block's barrier
// vmcnt-drain overlaps the other block's compute (the R6/R7 232us was a
// 1-block/CU exposed-HBM-latency floor).
//
// Wave w: st = w>>2 (s-tile), kq = w&3 (QK k-quarter = PV h-quarter).
//   dt_hi/dt_lo [16][DTP]  row-major bf16 hi/lo of desc tile (QK A-operand)
//   vt [768][16]           transposed hi tile, XOR-swizzled (l ^ 8*(h&1)),
//                          also overlaid as QK-partial scratch (8 KB) between
//                          B_b and B_d (barrier-separated from vt use).
// QK: k-split 192/wave, q (hi/lo) loaded per tile (L2-hot, keeps VGPR<=128);
// softmax in-register on kq=0 waves; PV: O^T = V^T * P^T with K=32 MFMA,
// zero-pa lanes g>=2 (K rows 16..31 multiply by zero).
// Block outputs UNNORMALIZED acc + (m_run, sum_run); k3_fin merges lh halves.
// ---------------------------------------------------------------------------
#define DTP 776                   // dt row pitch (hw): bank-spread (97 mod 8)

extern "C" __global__ __launch_bounds__(512, 4)
void k2f(const unsigned short* __restrict__ qhi,
         const unsigned short* __restrict__ qlo,
         const float* __restrict__ desc,
         float* __restrict__ Opart, float* __restrict__ ms)
{
    __shared__ __align__(16) unsigned short dt_hi[TL*DTP];   // 24832 B
    __shared__ __align__(16) unsigned short dt_lo[TL*DTP];   // 24832 B
    __shared__ __align__(16) unsigned short vt[NH*16];       // 24576 B (+overlay)
    __shared__ short4v p2[2][16][5];                         // 1280 B
    __shared__ float  f_lds[2][16];                          // 128 B

    const int b = blockIdx.x, lh = blockIdx.y, t = threadIdx.x;
    const int w = t >> 6, L = t & 63;
    const int st = w >> 2, kq = w & 3;        // kq doubles as PV h-quarter
    const int g = L >> 4, r16 = L & 15;

    const float* dsrc = desc + ((size_t)b*NL + (size_t)lh*256)*NH;

    const int s_in = 16*st + r16;
    const size_t qrow = ((size_t)b*NS + (s_in < NS ? s_in : NS-1))*(size_t)NH;

    f32x4 acc[12];
    #pragma unroll
    for (int ht = 0; ht < 12; ++ht) acc[ht] = (f32x4){0.f,0.f,0.f,0.f};

    float m_run = -1e30f, sum_run = 0.f;

    // staging regs: 6 float4/thread (tile = 16 x 768 f32)
    f32x4 sreg[6];
    #pragma unroll
    for (int i = 0; i < 6; ++i)
        sreg[i] = *(const f32x4*)(dsrc + (size_t)(t + 512*i)*4);   // tile 0

    #pragma unroll 1
    for (int tt = 0; tt < NT; ++tt) {
        // ---- stage dt: f32 regs -> bf16 hi/lo row-major (b64 writes) ----
        #pragma unroll
        for (int i = 0; i < 6; ++i) {
            const int v = t + 512*i;
            const int l = v/192, h = 4*(v%192);
            ushort4v hi4, lo4;
            #pragma unroll
            for (int c = 0; c < 4; ++c) {
                const float x = sreg[i][c];
                const unsigned short hh = bf16_rne(x);
                hi4[c] = hh;
                lo4[c] = bf16_rne(x - bf16f(hh));
            }
            *(ushort4v*)&dt_hi[l*DTP + h] = hi4;
            *(ushort4v*)&dt_lo[l*DTP + h] = lo4;
        }

        // ---- vt gather (second read, L2-hot) + convert to bf16 in regs ----
        ushort8v v0bf[3];
        {
            const float* gsrc = dsrc + (size_t)tt*TL*NH;
            #pragma unroll
            for (int rep = 0; rep < 3; ++rep) {
                const int u = 512*rep + t;
                const int h = u >> 1, half = u & 1;
                #pragma unroll
                for (int e = 0; e < 8; ++e)
                    v0bf[rep][e] = bf16_rne(gsrc[(size_t)(8*half + e)*NH + h]);
            }
        }

        // ---- issue next tile's sreg loads (drained at B_b; the stall is
        //      absorbed by the co-resident block) ----
        if (tt < NT-1) {
            const float* nsrc = dsrc + (size_t)(tt+1)*TL*NH;
            #pragma unroll
            for (int i = 0; i < 6; ++i)
                sreg[i] = *(const f32x4*)(nsrc + (size_t)(t + 512*i)*4);
        }
        __syncthreads();   // B_b: dt ready

        // ---- QK^T partial: wave (st,kq) covers k in [192kq, 192kq+192) ----
        f32x4 Se = (f32x4){0.f,0.f,0.f,0.f};
        #pragma unroll
        for (int kb = 0; kb < 6; ++kb) {
            const int k0 = 192*kq + 32*kb;
            const bf16x8 Bh = *(const bf16x8*)&qhi[qrow + k0 + 8*g];
            const bf16x8 Bl = *(const bf16x8*)&qlo[qrow + k0 + 8*g];
            const bf16x8 Ah = *(const bf16x8*)&dt_hi[r16*DTP + k0 + 8*g];
            const bf16x8 Al = *(const bf16x8*)&dt_lo[r16*DTP + k0 + 8*g];
            Se = MFMA16(Ah, Bh, Se, 0,0,0);
            Se = MFMA16(Al, Bh, Se, 0,0,0);
            Se = MFMA16(Ah, Bl, Se, 0,0,0);
        }
        ((f32x4*)vt)[(st*4 + kq)*64 + L] = Se;   // scratch overlay
        __syncthreads();   // B_c: partials ready

        // ---- kq=0 waves: reduce partials + online softmax ----
        if (kq == 0) {
            #pragma unroll
            for (int o = 1; o < 4; ++o)
                Se += ((const f32x4*)vt)[(st*4 + o)*64 + L];
            // lane holds S^T[l = 4g+r][s = r16]
            float pm = fmaxf(fmaxf(Se[0],Se[1]), fmaxf(Se[2],Se[3]));
            pm = fmaxf(pm, __shfl_xor(pm, 16));
            pm = fmaxf(pm, __shfl_xor(pm, 32));
            const float mnew = fmaxf(m_run, pm);
            const float fsc  = __expf(m_run - mnew);
            float pe[4];
            #pragma unroll
            for (int r = 0; r < 4; ++r) pe[r] = __expf(Se[r] - mnew);
            float ts = (pe[0]+pe[1]) + (pe[2]+pe[3]);
            ts += __shfl_xor(ts, 16);
            ts += __shfl_xor(ts, 32);
            sum_run = sum_run*fsc + ts;
            m_run = mnew;
            short4v pev;
            #pragma unroll
            for (int r = 0; r < 4; ++r) pev[r] = (short)bf16_rne(pe[r]);
            p2[st][r16][g] = pev;                 // l = 4g+r
            if (L < 16) f_lds[st][L] = fsc;
        }
        __syncthreads();   // B_d: p2/f ready; scratch reads done -> vt free

        // ---- vt writes: v0bf -> XOR-swizzled transposed tile ----
        #pragma unroll
        for (int rep = 0; rep < 3; ++rep) {
            const int u = 512*rep + t;
            const int h = u >> 1, half = u & 1;
            *(ushort8v*)&vt[h*16 + ((8*half) ^ ((h&1)<<3))] = v0bf[rep];
        }
        __syncthreads();   // B_e: vt ready

        // ---- PV: O^T = V^T * P^T (K=32, zero-padded rows 16..31) ----
        bf16x8 pa;
        if (g < 2) {
            const short4v a0 = p2[st][r16][2*g];
            const short4v a1 = p2[st][r16][2*g + 1];
            pa = __builtin_shufflevector(a0, a1, 0,1,2,3,4,5,6,7);
        } else {
            pa = (bf16x8){0,0,0,0,0,0,0,0};
        }
        const float f = f_lds[st][r16];
        #pragma unroll
        for (int ht = 0; ht < 12; ++ht) {
            acc[ht][0] *= f; acc[ht][1] *= f;
            acc[ht][2] *= f; acc[ht][3] *= f;
        }
        #pragma unroll
        for (int ht = 0; ht < 12; ++ht) {
            const int hrow = 16*(12*kq + ht) + r16;     // A row m = r16
            const bf16x8 av =
                *(const bf16x8*)&vt[hrow*16 + ((8*(g&1)) ^ ((hrow&1)<<3))];
            acc[ht] = MFMA16(av, pa, acc[ht], 0,0,0);
        }
    }

    // ---- store unnormalized partials + (m, sum) ----
    const int s = 16*st + r16;
    if (s < NS) {
        float* Ob = Opart + ((size_t)(b*2 + lh)*NS + s)*NH;
        #pragma unroll
        for (int ht = 0; ht < 12; ++ht)
            *(f32x4*)&Ob[16*(12*kq + ht) + 4*g] = acc[ht];
    }
    if (kq == 0 && L < 16) {
        const int s2 = 16*st + L;
        if (s2 < NS) {
            ms[((size_t)(b*2 + lh)*NS + s2)*2 + 0] = m_run;
            ms[((size_t)(b*2 + lh)*NS + s2)*2 + 1] = sum_run;
        }
    }
}

// ---------------------------------------------------------------------------
// K3: merge the two l-half partials per (b,s):
//   out = (e^{m0-m} O0 + e^{m1-m} O1) / (e^{m0-m} s0 + e^{m1-m} s1)
// ---------------------------------------------------------------------------
extern "C" __global__ __launch_bounds__(256)
void k3_fin(const float* __restrict__ Opart, const float* __restrict__ ms,
            float* __restrict__ out)
{
    __shared__ float c0s[NS], c1s[NS];
    const int b = blockIdx.x, t = threadIdx.x;
    if (t < NS) {
        const float m0 = ms[((size_t)(b*2 + 0)*NS + t)*2 + 0];
        const float s0 = ms[((size_t)(b*2 + 0)*NS + t)*2 + 1];
        const float m1 = ms[((size_t)(b*2 + 1)*NS + t)*2 + 0];
        const float s1 = ms[((size_t)(b*2 + 1)*NS + t)*2 + 1];
        const float m  = fmaxf(m0, m1);
        const float e0 = __expf(m0 - m), e1 = __expf(m1 - m);
        const float inv = 1.0f / (e0*s0 + e1*s1);
        c0s[t] = e0*inv;
        c1s[t] = e1*inv;
    }
    __syncthreads();
    const float* O0 = Opart + (size_t)(b*2 + 0)*NS*NH;
    const float* O1 = Opart + (size_t)(b*2 + 1)*NS*NH;
    #pragma unroll 1
    for (int i4 = t; i4 < NS*NH/4; i4 += 256) {
        const int idx = 4*i4;
        const int s = idx / NH, h = idx - s*NH;
        const f32x4 a = *(const f32x4*)&O0[idx];
        const f32x4 c = *(const f32x4*)&O1[idx];
        const float c0 = c0s[s], c1 = c1s[s];
        f32x4 o;
        o[0] = c0*a[0] + c1*c[0]; o[1] = c0*a[1] + c1*c[1];
        o[2] = c0*a[2] + c1*c[2]; o[3] = c0*a[3] + c1*c[3];
        *(f32x4*)&out[(size_t)b*ROWE + (size_t)s*(ND+NH) + ND + h] = o;
    }
}

// ---------------------------------------------------------------------------
extern "C" void kernel_launch(void* const* d_in, const int* in_sizes, int n_in,
                              void* d_out, int out_size, void* d_ws, size_t ws_size,
                              hipStream_t stream)
{
    const int*   skills = (const int*)  d_in[0];
    const float* desc   = (const float*)d_in[1];
    const float* embs   = (const float*)d_in[2];
    const float* W      = (const float*)d_in[3];
    float* out = (float*)d_out;

    unsigned short* qhi = (unsigned short*)d_ws;          // [NB][NS][NH] bf16
    unsigned short* qlo = qhi + (size_t)NB*NS*NH;         // [NB][NS][NH] bf16
    float* Opart = (float*)(qlo + (size_t)NB*NS*NH);      // [NB*2][NS][NH] f32
    float* ms    = Opart + (size_t)NB*2*NS*NH;            // [NB*2][NS][2]  f32

    k1_q  <<<NB,          256, 0, stream>>>(skills, embs, W, qhi, qlo, out);
    k2f   <<<dim3(NB, 2), 512, 0, stream>>>(qhi, qlo, desc, Opart, ms);
    k3_fin<<<NB,          256, 0, stream>>>(Opart, ms, out);
}

// Round 9
// 360.924 us; speedup vs baseline: 1.5672x; 1.5672x over previous
//
#include <hip/hip_runtime.h>
#include <cstddef>
#include <cstdint>

#define NB 256
#define NS 20
#define NL 512
#define ND 128
#define NH 768
#define ROWE (NS*(ND+NH))   // 17920 floats per output row
#define TL 16               // l-rows per sub-tile
#define NPAIR 8             // pairs of sub-tiles per block (256 l total)

typedef __attribute__((ext_vector_type(4))) float  f32x4;
typedef __attribute__((ext_vector_type(8))) short  bf16x8;
typedef __attribute__((ext_vector_type(4))) short  short4v;
typedef __attribute__((ext_vector_type(4))) unsigned short ushort4v;
typedef __attribute__((ext_vector_type(8))) unsigned short ushort8v;

#define MFMA16 __builtin_amdgcn_mfma_f32_16x16x32_bf16

__device__ __forceinline__ unsigned short bf16_rne(float v){
    unsigned u = __builtin_bit_cast(unsigned, v);
    u = (u + 0x7fffu + ((u>>16)&1u)) >> 16;
    return (unsigned short)u;
}
__device__ __forceinline__ float bf16f(unsigned short h){
    unsigned u = ((unsigned)h)<<16;
    return __builtin_bit_cast(float, u);
}
// LDS-only barrier: do NOT drain vmcnt (global prefetches stay in flight).
// All inter-wave dependencies in k2f go through LDS; no intra-kernel global
// RAW exists, so this is safe (m201 8-phase template pattern).
__device__ __forceinline__ void bar_lds(){
    asm volatile("s_waitcnt lgkmcnt(0)" ::: "memory");
    __builtin_amdgcn_s_barrier();
}

// ---------------------------------------------------------------------------
// K1: se = embs[skills[b]] -> out (concat left part);  q = se @ W -> bf16
// hi/lo arrays in ws. 256 blocks x 256 threads; wave w owns s in [5w,5w+5).
// ---------------------------------------------------------------------------
extern "C" __global__ __launch_bounds__(256)
void k1_q(const int* __restrict__ skills, const float* __restrict__ embs,
          const float* __restrict__ W,
          unsigned short* __restrict__ qhi, unsigned short* __restrict__ qlo,
          float* __restrict__ out)
{
    __shared__ float se[NS*ND];
    __shared__ int   sk[NS];
    const int b = blockIdx.x, t = threadIdx.x;
    if (t < NS) sk[t] = skills[b*NS + t];
    __syncthreads();
    for (int idx = t; idx < NS*ND; idx += 256) {
        const int s = idx >> 7, d = idx & (ND-1);
        const float v = embs[(size_t)sk[s]*ND + d];
        se[idx] = v;
        out[(size_t)b*ROWE + (size_t)s*(ND+NH) + d] = v;
    }
    __syncthreads();

    const int w = t >> 6, lane = t & 63;
    float acc[5][12];
    #pragma unroll
    for (int i = 0; i < 5; ++i)
        #pragma unroll
        for (int c = 0; c < 12; ++c) acc[i][c] = 0.f;

    const float* Wl = W + lane;
    for (int d4 = 0; d4 < ND/4; ++d4) {
        f32x4 sv[5];
        #pragma unroll
        for (int i = 0; i < 5; ++i)
            sv[i] = *(const f32x4*)&se[(5*w + i)*ND + 4*d4];
        #pragma unroll
        for (int r = 0; r < 4; ++r) {
            const float* wr = Wl + (size_t)(4*d4 + r)*NH;
            float wv[12];
            #pragma unroll
            for (int c = 0; c < 12; ++c) wv[c] = wr[64*c];
            #pragma unroll
            for (int i = 0; i < 5; ++i) {
                const float s_ = sv[i][r];
                #pragma unroll
                for (int c = 0; c < 12; ++c) acc[i][c] += s_*wv[c];
            }
        }
    }
    #pragma unroll
    for (int i = 0; i < 5; ++i)
        #pragma unroll
        for (int c = 0; c < 12; ++c) {
            const size_t idx = ((size_t)b*NS + 5*w + i)*NH + lane + 64*c;
            const float v = acc[i][c];
            const unsigned short hh = bf16_rne(v);
            qhi[idx] = hh;
            qlo[idx] = bf16_rne(v - bf16f(hh));
        }
}

// ---------------------------------------------------------------------------
// K2F: flash-attention partial over an l-range of 256.  Grid (NB,2); block
// (b,lh) does 8 pairs of 16-row sub-tiles.  512 threads (8 waves), LDS 66.9 KB
// -> 2 blocks/CU; barriers are LDS-only (no vmcnt drain) so global prefetches
// pipeline across phases and the co-resident block hides remaining latency.
//
// Wave w: st = w>>2 (s-tile), kq = w&3 (QK k-quarter = PV h-quarter).
//   dt_hi/dt_lo [16][DTP]  row-major bf16 hi/lo of one sub-tile (QK A-operand)
//   vt [768][32]           transposed pair tile (PV A-operand), chunk-XOR
//                          swizzled, OVERLAID on the dt region (phase-disjoint)
//   scr[2][512]            QK partial-score scratch (separate region)
// Per pair: stage t0 | QK-a | stage t1 + gather vt + prefetch | QK-b |
// pair-softmax (kq0) + vt write | PV (K=32, both halves real).
// Outputs UNNORMALIZED acc + (m,sum); k3_fin merges the lh halves.
// ---------------------------------------------------------------------------
#define DTP 776                   // dt row pitch (hw)

extern "C" __global__ __launch_bounds__(512)
void k2f(const unsigned short* __restrict__ qhi,
         const unsigned short* __restrict__ qlo,
         const float* __restrict__ desc,
         float* __restrict__ Opart, float* __restrict__ ms)
{
    __shared__ __align__(16) unsigned short dtvt[2*TL*DTP];  // 49664 B
    __shared__ __align__(16) f32x4 scr[2][512];              // 16384 B
    __shared__ short4v p2[2][16][9];                         // 2304 B
    __shared__ float  f_lds[2][16];                          // 128 B
    unsigned short* dt_hi = dtvt;
    unsigned short* dt_lo = dtvt + TL*DTP;
    unsigned short* vt    = dtvt;          // [768][32] swizzled, overlay

    const int b = blockIdx.x, lh = blockIdx.y, t = threadIdx.x;
    const int w = t >> 6, L = t & 63;
    const int st = w >> 2, kq = w & 3;     // kq doubles as PV h-quarter
    const int g = L >> 4, r16 = L & 15;

    const float* dsrc = desc + ((size_t)b*NL + (size_t)lh*256)*NH;
    const int s_in = 16*st + r16;
    const size_t qrow = ((size_t)b*NS + (s_in < NS ? s_in : NS-1))*(size_t)NH;

    f32x4 acc[12];
    #pragma unroll
    for (int ht = 0; ht < 12; ++ht) acc[ht] = (f32x4){0.f,0.f,0.f,0.f};
    float m_run = -1e30f, sum_run = 0.f;

    // staging regs: 6 f32x4/thread = one 16x768 sub-tile (linear, coalesced)
    f32x4 sreg[6];
    #pragma unroll
    for (int i = 0; i < 6; ++i)
        sreg[i] = *(const f32x4*)(dsrc + (size_t)(t + 512*i)*4);

    #pragma unroll 1
    for (int pp = 0; pp < NPAIR; ++pp) {
        bar_lds();   // B0: prior PV done reading vt -> dt region free

        // ---- stage dt(t0) ----
        #pragma unroll
        for (int i = 0; i < 6; ++i) {
            const int v = t + 512*i;
            const int l = v/192, h = 4*(v%192);
            ushort4v hi4, lo4;
            #pragma unroll
            for (int c = 0; c < 4; ++c) {
                const float x = sreg[i][c];
                const unsigned short hh = bf16_rne(x);
                hi4[c] = hh;
                lo4[c] = bf16_rne(x - bf16f(hh));
            }
            *(ushort4v*)&dt_hi[l*DTP + h] = hi4;
            *(ushort4v*)&dt_lo[l*DTP + h] = lo4;
        }
        // reload sreg with t1 rows (in flight across QK-a)
        {
            const float* s1 = dsrc + (size_t)(pp*32 + 16)*NH;
            #pragma unroll
            for (int i = 0; i < 6; ++i)
                sreg[i] = *(const f32x4*)(s1 + (size_t)(t + 512*i)*4);
        }
        bar_lds();   // B1: dt(t0) ready

        // ---- QK-a: k-slice [192kq, 192kq+192) over t0 rows ----
        f32x4 SeA = (f32x4){0.f,0.f,0.f,0.f};
        #pragma unroll
        for (int kb = 0; kb < 6; ++kb) {
            const int k0 = 192*kq + 32*kb;
            const bf16x8 Bh = *(const bf16x8*)&qhi[qrow + k0 + 8*g];
            const bf16x8 Bl = *(const bf16x8*)&qlo[qrow + k0 + 8*g];
            const bf16x8 Ah = *(const bf16x8*)&dt_hi[r16*DTP + k0 + 8*g];
            const bf16x8 Al = *(const bf16x8*)&dt_lo[r16*DTP + k0 + 8*g];
            SeA = MFMA16(Ah, Bh, SeA, 0,0,0);
            SeA = MFMA16(Al, Bh, SeA, 0,0,0);
            SeA = MFMA16(Ah, Bl, SeA, 0,0,0);
        }
        scr[0][(st*4 + kq)*64 + L] = SeA;
        bar_lds();   // B2: QK-a done with dt(t0); scrA written

        // ---- stage dt(t1) ----
        #pragma unroll
        for (int i = 0; i < 6; ++i) {
            const int v = t + 512*i;
            const int l = v/192, h = 4*(v%192);
            ushort4v hi4, lo4;
            #pragma unroll
            for (int c = 0; c < 4; ++c) {
                const float x = sreg[i][c];
                const unsigned short hh = bf16_rne(x);
                hi4[c] = hh;
                lo4[c] = bf16_rne(x - bf16f(hh));
            }
            *(ushort4v*)&dt_hi[l*DTP + h] = hi4;
            *(ushort4v*)&dt_lo[l*DTP + h] = lo4;
        }
        // vt gather (second read of pair rows; L2-hot), bf16 in regs
        ushort8v v0bf[6];
        {
            const float* gsrc = dsrc + (size_t)pp*32*NH;
            #pragma unroll
            for (int rep = 0; rep < 6; ++rep) {
                const int u = 512*rep + t;
                const int h = u >> 2, q4 = u & 3;
                #pragma unroll
                for (int e = 0; e < 8; ++e)
                    v0bf[rep][e] = bf16_rne(gsrc[(size_t)(8*q4 + e)*NH + h]);
            }
        }
        // prefetch next pair's t0 rows (in flight across QK-b + softmax + PV)
        if (pp < NPAIR-1) {
            const float* s2 = dsrc + (size_t)(pp + 1)*32*NH;
            #pragma unroll
            for (int i = 0; i < 6; ++i)
                sreg[i] = *(const f32x4*)(s2 + (size_t)(t + 512*i)*4);
        }
        bar_lds();   // B3: dt(t1) ready

        // ---- QK-b ----
        f32x4 SeB = (f32x4){0.f,0.f,0.f,0.f};
        #pragma unroll
        for (int kb = 0; kb < 6; ++kb) {
            const int k0 = 192*kq + 32*kb;
            const bf16x8 Bh = *(const bf16x8*)&qhi[qrow + k0 + 8*g];
            const bf16x8 Bl = *(const bf16x8*)&qlo[qrow + k0 + 8*g];
            const bf16x8 Ah = *(const bf16x8*)&dt_hi[r16*DTP + k0 + 8*g];
            const bf16x8 Al = *(const bf16x8*)&dt_lo[r16*DTP + k0 + 8*g];
            SeB = MFMA16(Ah, Bh, SeB, 0,0,0);
            SeB = MFMA16(Al, Bh, SeB, 0,0,0);
            SeB = MFMA16(Ah, Bl, SeB, 0,0,0);
        }
        scr[1][(st*4 + kq)*64 + L] = SeB;
        bar_lds();   // B4: scratches ready; dt region free for vt

        // ---- pair softmax (kq==0 waves): 32 l-rows at once ----
        if (kq == 0) {
            #pragma unroll
            for (int o = 1; o < 4; ++o) {
                SeA += scr[0][(st*4 + o)*64 + L];
                SeB += scr[1][(st*4 + o)*64 + L];
            }
            float pm = fmaxf(fmaxf(fmaxf(SeA[0],SeA[1]), fmaxf(SeA[2],SeA[3])),
                             fmaxf(fmaxf(SeB[0],SeB[1]), fmaxf(SeB[2],SeB[3])));
            pm = fmaxf(pm, __shfl_xor(pm, 16));
            pm = fmaxf(pm, __shfl_xor(pm, 32));
            const float mnew = fmaxf(m_run, pm);
            const float fsc  = __expf(m_run - mnew);
            float peA[4], peB[4];
            #pragma unroll
            for (int r = 0; r < 4; ++r) {
                peA[r] = __expf(SeA[r] - mnew);
                peB[r] = __expf(SeB[r] - mnew);
            }
            float ts = (peA[0]+peA[1]+peA[2]+peA[3])
                     + (peB[0]+peB[1]+peB[2]+peB[3]);
            ts += __shfl_xor(ts, 16);
            ts += __shfl_xor(ts, 32);
            sum_run = sum_run*fsc + ts;
            m_run = mnew;
            short4v pevA, pevB;
            #pragma unroll
            for (int r = 0; r < 4; ++r) {
                pevA[r] = (short)bf16_rne(peA[r]);   // l = 4g+r
                pevB[r] = (short)bf16_rne(peB[r]);   // l = 16+4g+r
            }
            p2[st][r16][g]     = pevA;
            p2[st][r16][4 + g] = pevB;
            if (L < 16) f_lds[st][L] = fsc;
        }
        // ---- vt writes: chunk-swizzled transposed pair tile (all waves) ----
        #pragma unroll
        for (int rep = 0; rep < 6; ++rep) {
            const int u = 512*rep + t;
            const int h = u >> 2, q4 = u & 3;
            *(ushort8v*)&vt[h*32 + 8*(q4 ^ (h & 3))] = v0bf[rep];
        }
        bar_lds();   // B5: vt + p2 + f ready

        // ---- PV: O^T = V^T * P^T, K=32 (both halves real) ----
        const short4v a0 = p2[st][r16][2*g];
        const short4v a1 = p2[st][r16][2*g + 1];
        const bf16x8 pa = __builtin_shufflevector(a0, a1, 0,1,2,3,4,5,6,7);
        const float f = f_lds[st][r16];
        #pragma unroll
        for (int ht = 0; ht < 12; ++ht) {
            acc[ht][0] *= f; acc[ht][1] *= f;
            acc[ht][2] *= f; acc[ht][3] *= f;
        }
        #pragma unroll
        for (int ht = 0; ht < 12; ++ht) {
            const int hrow = 16*(12*kq + ht) + r16;   // A row m = r16
            const bf16x8 av =
                *(const bf16x8*)&vt[hrow*32 + 8*(g ^ (hrow & 3))];
            acc[ht] = MFMA16(av, pa, acc[ht], 0,0,0);
        }
    }

    // ---- store unnormalized partials + (m, sum) ----
    const int s = 16*st + r16;
    if (s < NS) {
        float* Ob = Opart + ((size_t)(b*2 + lh)*NS + s)*NH;
        #pragma unroll
        for (int ht = 0; ht < 12; ++ht)
            *(f32x4*)&Ob[16*(12*kq + ht) + 4*g] = acc[ht];
    }
    if (kq == 0 && L < 16) {
        const int s2 = 16*st + L;
        if (s2 < NS) {
            ms[((size_t)(b*2 + lh)*NS + s2)*2 + 0] = m_run;
            ms[((size_t)(b*2 + lh)*NS + s2)*2 + 1] = sum_run;
        }
    }
}

// ---------------------------------------------------------------------------
// K3: merge the two l-half partials per (b,s):
//   out = (e^{m0-m} O0 + e^{m1-m} O1) / (e^{m0-m} s0 + e^{m1-m} s1)
// ---------------------------------------------------------------------------
extern "C" __global__ __launch_bounds__(256)
void k3_fin(const float* __restrict__ Opart, const float* __restrict__ ms,
            float* __restrict__ out)
{
    __shared__ float c0s[NS], c1s[NS];
    const int b = blockIdx.x, t = threadIdx.x;
    if (t < NS) {
        const float m0 = ms[((size_t)(b*2 + 0)*NS + t)*2 + 0];
        const float s0 = ms[((size_t)(b*2 + 0)*NS + t)*2 + 1];
        const float m1 = ms[((size_t)(b*2 + 1)*NS + t)*2 + 0];
        const float s1 = ms[((size_t)(b*2 + 1)*NS + t)*2 + 1];
        const float m  = fmaxf(m0, m1);
        const float e0 = __expf(m0 - m), e1 = __expf(m1 - m);
        const float inv = 1.0f / (e0*s0 + e1*s1);
        c0s[t] = e0*inv;
        c1s[t] = e1*inv;
    }
    __syncthreads();
    const float* O0 = Opart + (size_t)(b*2 + 0)*NS*NH;
    const float* O1 = Opart + (size_t)(b*2 + 1)*NS*NH;
    #pragma unroll 1
    for (int i4 = t; i4 < NS*NH/4; i4 += 256) {
        const int idx = 4*i4;
        const int s = idx / NH, h = idx - s*NH;
        const f32x4 a = *(const f32x4*)&O0[idx];
        const f32x4 c = *(const f32x4*)&O1[idx];
        const float c0 = c0s[s], c1 = c1s[s];
        f32x4 o;
        o[0] = c0*a[0] + c1*c[0]; o[1] = c0*a[1] + c1*c[1];
        o[2] = c0*a[2] + c1*c[2]; o[3] = c0*a[3] + c1*c[3];
        *(f32x4*)&out[(size_t)b*ROWE + (size_t)s*(ND+NH) + ND + h] = o;
    }
}

// ---------------------------------------------------------------------------
extern "C" void kernel_launch(void* const* d_in, const int* in_sizes, int n_in,
                              void* d_out, int out_size, void* d_ws, size_t ws_size,
                              hipStream_t stream)
{
    const int*   skills = (const int*)  d_in[0];
    const float* desc   = (const float*)d_in[1];
    const float* embs   = (const float*)d_in[2];
    const float* W      = (const float*)d_in[3];
    float* out = (float*)d_out;

    unsigned short* qhi = (unsigned short*)d_ws;          // [NB][NS][NH] bf16
    unsigned short* qlo = qhi + (size_t)NB*NS*NH;         // [NB][NS][NH] bf16
    float* Opart = (float*)(qlo + (size_t)NB*NS*NH);      // [NB*2][NS][NH] f32
    float* ms    = Opart + (size_t)NB*2*NS*NH;            // [NB*2][NS][2]  f32

    k1_q  <<<NB,          256, 0, stream>>>(skills, embs, W, qhi, qlo, out);
    k2f   <<<dim3(NB, 2), 512, 0, stream>>>(qhi, qlo, desc, Opart, ms);
    k3_fin<<<NB,          256, 0, stream>>>(Opart, ms, out);
}

// Round 10
// 268.799 us; speedup vs baseline: 2.1043x; 1.3427x over previous
//
#include <hip/hip_runtime.h>
#include <cstddef>
#include <cstdint>

#define NB 256
#define NS 20
#define NL 512
#define ND 128
#define NH 768
#define ROWE (NS*(ND+NH))   // 17920 floats per output row

typedef __attribute__((ext_vector_type(4))) float  f32x4;
typedef __attribute__((ext_vector_type(8))) short  bf16x8;
typedef __attribute__((ext_vector_type(4))) unsigned short ushort4v;

#define MFMA16 __builtin_amdgcn_mfma_f32_16x16x32_bf16

__device__ __forceinline__ unsigned short bf16_rne(float v){
    unsigned u = __builtin_bit_cast(unsigned, v);
    u = (u + 0x7fffu + ((u>>16)&1u)) >> 16;
    return (unsigned short)u;
}
__device__ __forceinline__ float bf16f(unsigned short h){
    unsigned u = ((unsigned)h)<<16;
    return __builtin_bit_cast(float, u);
}
// LDS-only barrier (no vmcnt drain): global prefetches stay in flight.
__device__ __forceinline__ void bar_lds(){
    asm volatile("s_waitcnt lgkmcnt(0)" ::: "memory");
    __builtin_amdgcn_s_barrier();
}

// ---------------------------------------------------------------------------
// K1: se = embs[skills[b]] -> out (concat left part);  q = se @ W -> bf16
// hi/lo arrays in ws. 256 blocks x 256 threads; wave w owns s in [5w,5w+5).
// ---------------------------------------------------------------------------
extern "C" __global__ __launch_bounds__(256)
void k1_q(const int* __restrict__ skills, const float* __restrict__ embs,
          const float* __restrict__ W,
          unsigned short* __restrict__ qhi, unsigned short* __restrict__ qlo,
          float* __restrict__ out)
{
    __shared__ float se[NS*ND];
    __shared__ int   sk[NS];
    const int b = blockIdx.x, t = threadIdx.x;
    if (t < NS) sk[t] = skills[b*NS + t];
    __syncthreads();
    for (int idx = t; idx < NS*ND; idx += 256) {
        const int s = idx >> 7, d = idx & (ND-1);
        const float v = embs[(size_t)sk[s]*ND + d];
        se[idx] = v;
        out[(size_t)b*ROWE + (size_t)s*(ND+NH) + d] = v;
    }
    __syncthreads();

    const int w = t >> 6, lane = t & 63;
    float acc[5][12];
    #pragma unroll
    for (int i = 0; i < 5; ++i)
        #pragma unroll
        for (int c = 0; c < 12; ++c) acc[i][c] = 0.f;

    const float* Wl = W + lane;
    for (int d4 = 0; d4 < ND/4; ++d4) {
        f32x4 sv[5];
        #pragma unroll
        for (int i = 0; i < 5; ++i)
            sv[i] = *(const f32x4*)&se[(5*w + i)*ND + 4*d4];
        #pragma unroll
        for (int r = 0; r < 4; ++r) {
            const float* wr = Wl + (size_t)(4*d4 + r)*NH;
            float wv[12];
            #pragma unroll
            for (int c = 0; c < 12; ++c) wv[c] = wr[64*c];
            #pragma unroll
            for (int i = 0; i < 5; ++i) {
                const float s_ = sv[i][r];
                #pragma unroll
                for (int c = 0; c < 12; ++c) acc[i][c] += s_*wv[c];
            }
        }
    }
    #pragma unroll
    for (int i = 0; i < 5; ++i)
        #pragma unroll
        for (int c = 0; c < 12; ++c) {
            const size_t idx = ((size_t)b*NS + 5*w + i)*NH + lane + 64*c;
            const float v = acc[i][c];
            const unsigned short hh = bf16_rne(v);
            qhi[idx] = hh;
            qlo[idx] = bf16_rne(v - bf16f(hh));
        }
}

// ---------------------------------------------------------------------------
// K2QK: scores[b,s,l] = q[b,s,:]·desc[b,l,:] via split-bf16 MFMA.
// Grid (NB,2); block (b,lh) covers l in [256lh, 256lh+256) as 16 tiles of 16.
// 512 threads (8 waves): st = w&1 (s-tile), kq = w>>1 (k-quarter, 192 each).
// q (hi/lo, this wave's k-quarter) hoisted to registers once.
// LDS 56 KB (dt hi/lo 16x776 + scr) -> 2 blocks/CU, 16 waves: the second
// block's compute covers this block's HBM stalls (R9 fix: no PV accumulator
// -> ~75 VGPR -> 128-class occupancy).
// Per tile: stage dt | B | QK (18 MFMA, LDS-only) + scr write | B | kq0:
// reduce 4 partials + f32x4 store (l-contiguous).  2 barriers/tile, LDS-only.
// ---------------------------------------------------------------------------
#define DTP 776

extern "C" __global__ __launch_bounds__(512)
void k2qk(const unsigned short* __restrict__ qhi,
          const unsigned short* __restrict__ qlo,
          const float* __restrict__ desc, float* __restrict__ scores)
{
    __shared__ __align__(16) unsigned short dt_hi[16*DTP];   // 24832 B
    __shared__ __align__(16) unsigned short dt_lo[16*DTP];   // 24832 B
    __shared__ __align__(16) f32x4 scr[3][2][64];            // 6144 B

    const int b = blockIdx.x, lh = blockIdx.y, t = threadIdx.x;
    const int w = t >> 6, L = t & 63;
    const int st = w & 1, kq = w >> 1;
    const int g = L >> 4, r16 = L & 15;

    const float* dsrc = desc + ((size_t)b*NL + (size_t)lh*256)*NH;

    // hoist q (hi/lo) for this wave's k-quarter
    const int s_in = 16*st + r16;
    const size_t qrow = ((size_t)b*NS + (s_in < NS ? s_in : NS-1))*(size_t)NH;
    bf16x8 qhreg[6], qlreg[6];
    #pragma unroll
    for (int kb = 0; kb < 6; ++kb) {
        const int k0 = 192*kq + 32*kb + 8*g;
        qhreg[kb] = *(const bf16x8*)&qhi[qrow + k0];
        qlreg[kb] = *(const bf16x8*)&qlo[qrow + k0];
    }

    // staging regs: 6 f32x4/thread = 16 x 768 f32 tile
    f32x4 sreg[6];
    #pragma unroll
    for (int i = 0; i < 6; ++i)
        sreg[i] = *(const f32x4*)(dsrc + (size_t)(t + 512*i)*4);

    #pragma unroll 1
    for (int tt = 0; tt < 16; ++tt) {
        // ---- stage dt: f32 regs -> bf16 hi/lo row-major ----
        #pragma unroll
        for (int i = 0; i < 6; ++i) {
            const int v = t + 512*i;
            const int l = v/192, h = 4*(v%192);
            ushort4v hi4, lo4;
            #pragma unroll
            for (int c = 0; c < 4; ++c) {
                const float x = sreg[i][c];
                const unsigned short hh = bf16_rne(x);
                hi4[c] = hh;
                lo4[c] = bf16_rne(x - bf16f(hh));
            }
            *(ushort4v*)&dt_hi[l*DTP + h] = hi4;
            *(ushort4v*)&dt_lo[l*DTP + h] = lo4;
        }
        // issue next tile's loads (in flight across QK of this tile)
        if (tt < 15) {
            const float* nsrc = dsrc + (size_t)(tt+1)*16*NH;
            #pragma unroll
            for (int i = 0; i < 6; ++i)
                sreg[i] = *(const f32x4*)(nsrc + (size_t)(t + 512*i)*4);
        }
        bar_lds();   // B1: dt ready

        // ---- QK^T partial: k in [192kq, 192kq+192), q in regs ----
        f32x4 Se = (f32x4){0.f,0.f,0.f,0.f};
        #pragma unroll
        for (int kb = 0; kb < 6; ++kb) {
            const int k0 = 192*kq + 32*kb;
            const bf16x8 Ah = *(const bf16x8*)&dt_hi[r16*DTP + k0 + 8*g];
            const bf16x8 Al = *(const bf16x8*)&dt_lo[r16*DTP + k0 + 8*g];
            Se = MFMA16(Ah, qhreg[kb], Se, 0,0,0);
            Se = MFMA16(Al, qhreg[kb], Se, 0,0,0);
            Se = MFMA16(Ah, qlreg[kb], Se, 0,0,0);
        }
        if (kq > 0) scr[kq-1][st][L] = Se;
        bar_lds();   // B2: QK done reading dt; scr ready

        // ---- kq==0 waves: reduce + store (others proceed to next stage;
        //      scr safe: rewritten only after next B1) ----
        if (kq == 0) {
            Se += scr[0][st][L];
            Se += scr[1][st][L];
            Se += scr[2][st][L];
            // lane holds S[l = tile + 4g + r][s = 16st + r16]
            const int s = 16*st + r16;
            if (s < NS) {
                const int lidx = lh*256 + tt*16 + 4*g;
                *(f32x4*)&scores[((size_t)b*NS + s)*NL + lidx] = Se;
            }
        }
    }
}

// ---------------------------------------------------------------------------
// K3: softmax over l (512) per (b,s) row; f32 scores -> bf16 attn.
// ---------------------------------------------------------------------------
extern "C" __global__ __launch_bounds__(128)
void k3_softmax(const float* __restrict__ scores,
                unsigned short* __restrict__ attn)
{
    const int r = blockIdx.x, t = threadIdx.x;
    const float* row = scores + (size_t)r*NL;
    f32x4 v = *(const f32x4*)&row[t*4];
    float m = fmaxf(fmaxf(v[0], v[1]), fmaxf(v[2], v[3]));
    #pragma unroll
    for (int off = 32; off; off >>= 1) m = fmaxf(m, __shfl_xor(m, off));
    __shared__ float redm[2];
    if ((t & 63) == 0) redm[t >> 6] = m;
    __syncthreads();
    m = fmaxf(redm[0], redm[1]);

    float e[4];
    #pragma unroll
    for (int c = 0; c < 4; ++c) e[c] = __expf(v[c] - m);
    float sum = (e[0] + e[1]) + (e[2] + e[3]);
    #pragma unroll
    for (int off = 32; off; off >>= 1) sum += __shfl_xor(sum, off);
    __shared__ float reds[2];
    if ((t & 63) == 0) reds[t >> 6] = sum;
    __syncthreads();
    sum = reds[0] + reds[1];
    const float inv = 1.0f / sum;
    ushort4v o;
    #pragma unroll
    for (int c = 0; c < 4; ++c) o[c] = bf16_rne(e[c]*inv);
    *(ushort4v*)&attn[(size_t)r*NL + t*4] = o;
}

// ---------------------------------------------------------------------------
// K4: out[b,s,h] = sum_l attn[b,s,l]*desc[b,l,h]  (VALU, transpose-free).
// Grid (NB,2): hh picks an h-half (384).  512 threads: x = t&127
// (h = 384hh + x + 128c, c<3), sg = t>>7 (s = 5sg+i, i<5).  desc rows
// coalesced; attn wave-uniform bf16 loads.  15 acc regs -> high occupancy.
// ---------------------------------------------------------------------------
extern "C" __global__ __launch_bounds__(512)
void k4_out(const unsigned short* __restrict__ attn,
            const float* __restrict__ desc, float* __restrict__ out)
{
    const int b = blockIdx.x, hh = blockIdx.y, t = threadIdx.x;
    const int x = t & 127, sg = t >> 7;
    float acc[5][3];
    #pragma unroll
    for (int i = 0; i < 5; ++i)
        #pragma unroll
        for (int c = 0; c < 3; ++c) acc[i][c] = 0.f;

    const float* descb = desc + (size_t)b*NL*NH + hh*384 + x;
    const unsigned short* attnb = attn + ((size_t)b*NS + sg*5)*NL;

    #pragma unroll 2
    for (int l4 = 0; l4 < NL; l4 += 4) {
        float d0[4], d1[4], d2[4];
        #pragma unroll
        for (int rr = 0; rr < 4; ++rr) {
            const float* dr = descb + (size_t)(l4 + rr)*NH;
            d0[rr] = dr[0]; d1[rr] = dr[128]; d2[rr] = dr[256];
        }
        #pragma unroll
        for (int i = 0; i < 5; ++i) {
            const ushort4v pv = *(const ushort4v*)&attnb[(size_t)i*NL + l4];
            float p[4];
            #pragma unroll
            for (int rr = 0; rr < 4; ++rr) p[rr] = bf16f(pv[rr]);
            acc[i][0] += p[0]*d0[0] + p[1]*d0[1] + p[2]*d0[2] + p[3]*d0[3];
            acc[i][1] += p[0]*d1[0] + p[1]*d1[1] + p[2]*d1[2] + p[3]*d1[3];
            acc[i][2] += p[0]*d2[0] + p[1]*d2[1] + p[2]*d2[2] + p[3]*d2[3];
        }
    }
    #pragma unroll
    for (int i = 0; i < 5; ++i)
        #pragma unroll
        for (int c = 0; c < 3; ++c)
            out[(size_t)b*ROWE + (size_t)(sg*5 + i)*(ND+NH) + ND
                + hh*384 + x + 128*c] = acc[i][c];
}

// ---------------------------------------------------------------------------
extern "C" void kernel_launch(void* const* d_in, const int* in_sizes, int n_in,
                              void* d_out, int out_size, void* d_ws, size_t ws_size,
                              hipStream_t stream)
{
    const int*   skills = (const int*)  d_in[0];
    const float* desc   = (const float*)d_in[1];
    const float* embs   = (const float*)d_in[2];
    const float* W      = (const float*)d_in[3];
    float* out = (float*)d_out;

    unsigned short* qhi  = (unsigned short*)d_ws;          // [NB][NS][NH] bf16
    unsigned short* qlo  = qhi + (size_t)NB*NS*NH;         // [NB][NS][NH] bf16
    float* scores = (float*)(qlo + (size_t)NB*NS*NH);      // [NB][NS][NL] f32
    unsigned short* attn = (unsigned short*)(scores + (size_t)NB*NS*NL);

    k1_q      <<<NB,          256, 0, stream>>>(skills, embs, W, qhi, qlo, out);
    k2qk      <<<dim3(NB, 2), 512, 0, stream>>>(qhi, qlo, desc, scores);
    k3_softmax<<<NB*NS,       128, 0, stream>>>(scores, attn);
    k4_out    <<<dim3(NB, 2), 512, 0, stream>>>(attn, desc, out);
}

// Round 11
// 263.642 us; speedup vs baseline: 2.1455x; 1.0196x over previous
//
#include <hip/hip_runtime.h>
#include <cstddef>
#include <cstdint>

#define NB 256
#define NS 20
#define NL 512
#define ND 128
#define NH 768
#define ROWE (NS*(ND+NH))   // 17920 floats per output row

typedef __attribute__((ext_vector_type(4))) float  f32x4;
typedef __attribute__((ext_vector_type(8))) short  bf16x8;
typedef __attribute__((ext_vector_type(4))) unsigned short ushort4v;
typedef __attribute__((ext_vector_type(8))) unsigned short ushort8v;

#define MFMA16 __builtin_amdgcn_mfma_f32_16x16x32_bf16

__device__ __forceinline__ unsigned short bf16_rne(float v){
    unsigned u = __builtin_bit_cast(unsigned, v);
    u = (u + 0x7fffu + ((u>>16)&1u)) >> 16;
    return (unsigned short)u;
}
__device__ __forceinline__ float bf16f(unsigned short h){
    unsigned u = ((unsigned)h)<<16;
    return __builtin_bit_cast(float, u);
}
// LDS-only barrier (no vmcnt drain): global prefetches stay in flight.
__device__ __forceinline__ void bar_lds(){
    asm volatile("s_waitcnt lgkmcnt(0)" ::: "memory");
    __builtin_amdgcn_s_barrier();
}

// ---------------------------------------------------------------------------
// K1: se = embs[skills[b]] -> out (concat left part);  q = se @ W -> bf16
// hi/lo arrays in ws. 256 blocks x 256 threads; wave w owns s in [5w,5w+5).
// ---------------------------------------------------------------------------
extern "C" __global__ __launch_bounds__(256)
void k1_q(const int* __restrict__ skills, const float* __restrict__ embs,
          const float* __restrict__ W,
          unsigned short* __restrict__ qhi, unsigned short* __restrict__ qlo,
          float* __restrict__ out)
{
    __shared__ float se[NS*ND];
    __shared__ int   sk[NS];
    const int b = blockIdx.x, t = threadIdx.x;
    if (t < NS) sk[t] = skills[b*NS + t];
    __syncthreads();
    for (int idx = t; idx < NS*ND; idx += 256) {
        const int s = idx >> 7, d = idx & (ND-1);
        const float v = embs[(size_t)sk[s]*ND + d];
        se[idx] = v;
        out[(size_t)b*ROWE + (size_t)s*(ND+NH) + d] = v;
    }
    __syncthreads();

    const int w = t >> 6, lane = t & 63;
    float acc[5][12];
    #pragma unroll
    for (int i = 0; i < 5; ++i)
        #pragma unroll
        for (int c = 0; c < 12; ++c) acc[i][c] = 0.f;

    const float* Wl = W + lane;
    for (int d4 = 0; d4 < ND/4; ++d4) {
        f32x4 sv[5];
        #pragma unroll
        for (int i = 0; i < 5; ++i)
            sv[i] = *(const f32x4*)&se[(5*w + i)*ND + 4*d4];
        #pragma unroll
        for (int r = 0; r < 4; ++r) {
            const float* wr = Wl + (size_t)(4*d4 + r)*NH;
            float wv[12];
            #pragma unroll
            for (int c = 0; c < 12; ++c) wv[c] = wr[64*c];
            #pragma unroll
            for (int i = 0; i < 5; ++i) {
                const float s_ = sv[i][r];
                #pragma unroll
                for (int c = 0; c < 12; ++c) acc[i][c] += s_*wv[c];
            }
        }
    }
    #pragma unroll
    for (int i = 0; i < 5; ++i)
        #pragma unroll
        for (int c = 0; c < 12; ++c) {
            const size_t idx = ((size_t)b*NS + 5*w + i)*NH + lane + 64*c;
            const float v = acc[i][c];
            const unsigned short hh = bf16_rne(v);
            qhi[idx] = hh;
            qlo[idx] = bf16_rne(v - bf16f(hh));
        }
}

// ---------------------------------------------------------------------------
// K2QK: scores[b,s,l] = q[b,s,:]·desc[b,l,:] via split-bf16 MFMA.
// Grid (NB,2); block (b,lh) covers l in [256lh,256lh+256) as 16 tiles of 16.
// 512 threads (8 waves): st = w&1 (s-tile), kq = w>>1 (k-quarter, 192 each).
// 2-tile-deep register prefetch (named sregA/sregB — rule #20), q hi/lo read
// from global inside the QK loop (L2-resident 61KB/b, frees 48 VGPR).
// LDS 56 KB -> 2 blocks/CU; barriers LDS-only so prefetches span phases.
// ---------------------------------------------------------------------------
#define DTP 776

extern "C" __global__ __launch_bounds__(512)
void k2qk(const unsigned short* __restrict__ qhi,
          const unsigned short* __restrict__ qlo,
          const float* __restrict__ desc, float* __restrict__ scores)
{
    __shared__ __align__(16) unsigned short dt_hi[16*DTP];   // 24832 B
    __shared__ __align__(16) unsigned short dt_lo[16*DTP];   // 24832 B
    __shared__ __align__(16) f32x4 scr[3][2][64];            // 6144 B

    const int b = blockIdx.x, lh = blockIdx.y, t = threadIdx.x;
    const int w = t >> 6, L = t & 63;
    const int st = w & 1, kq = w >> 1;
    const int g = L >> 4, r16 = L & 15;

    const float* dsrc = desc + ((size_t)b*NL + (size_t)lh*256)*NH;
    const int s_in = 16*st + r16;
    const size_t qrow = ((size_t)b*NS + (s_in < NS ? s_in : NS-1))*(size_t)NH;

    auto tile_body = [&](f32x4 (&sreg)[6], int tt) {
        // ---- stage dt: f32 regs -> bf16 hi/lo row-major ----
        #pragma unroll
        for (int i = 0; i < 6; ++i) {
            const int v = t + 512*i;
            const int l = v/192, h = 4*(v%192);
            ushort4v hi4, lo4;
            #pragma unroll
            for (int c = 0; c < 4; ++c) {
                const float x = sreg[i][c];
                const unsigned short hh = bf16_rne(x);
                hi4[c] = hh;
                lo4[c] = bf16_rne(x - bf16f(hh));
            }
            *(ushort4v*)&dt_hi[l*DTP + h] = hi4;
            *(ushort4v*)&dt_lo[l*DTP + h] = lo4;
        }
        // ---- reissue this buffer with tile tt+2 (2-deep prefetch) ----
        if (tt < 14) {
            const float* nsrc = dsrc + (size_t)(tt+2)*16*NH;
            #pragma unroll
            for (int i = 0; i < 6; ++i)
                sreg[i] = *(const f32x4*)(nsrc + (size_t)4*(t + 512*i));
        }
        bar_lds();   // B1: dt ready

        // ---- QK^T partial: k in [192kq,192kq+192), q from global (L2) ----
        f32x4 Se = (f32x4){0.f,0.f,0.f,0.f};
        #pragma unroll
        for (int kb = 0; kb < 6; ++kb) {
            const int k0 = 192*kq + 32*kb;
            const bf16x8 Bh = *(const bf16x8*)&qhi[qrow + k0 + 8*g];
            const bf16x8 Bl = *(const bf16x8*)&qlo[qrow + k0 + 8*g];
            const bf16x8 Ah = *(const bf16x8*)&dt_hi[r16*DTP + k0 + 8*g];
            const bf16x8 Al = *(const bf16x8*)&dt_lo[r16*DTP + k0 + 8*g];
            Se = MFMA16(Ah, Bh, Se, 0,0,0);
            Se = MFMA16(Al, Bh, Se, 0,0,0);
            Se = MFMA16(Ah, Bl, Se, 0,0,0);
        }
        if (kq > 0) scr[kq-1][st][L] = Se;
        bar_lds();   // B2: QK done reading dt; scr ready

        if (kq == 0) {
            Se += scr[0][st][L];
            Se += scr[1][st][L];
            Se += scr[2][st][L];
            const int s = 16*st + r16;   // lane: S[l=tile+4g+r][s]
            if (s < NS) {
                const int lidx = lh*256 + tt*16 + 4*g;
                *(f32x4*)&scores[((size_t)b*NS + s)*NL + lidx] = Se;
            }
        }
    };

    f32x4 sregA[6], sregB[6];
    #pragma unroll
    for (int i = 0; i < 6; ++i)
        sregA[i] = *(const f32x4*)(dsrc + (size_t)4*(t + 512*i));
    #pragma unroll
    for (int i = 0; i < 6; ++i)
        sregB[i] = *(const f32x4*)(dsrc + 16*NH + (size_t)4*(t + 512*i));

    #pragma unroll 1
    for (int tp = 0; tp < 8; ++tp) {
        tile_body(sregA, 2*tp);
        tile_body(sregB, 2*tp + 1);
    }
}

// ---------------------------------------------------------------------------
// K4: softmax (in-LDS) + out[b,s,h] = sum_l attn*desc.  Grid (NB,2): hh picks
// an h-half (384).  384 threads.  Phase 1: scores[b] (40KB) -> LDS; 6 waves
// softmax 20 rows -> bf16 attn LDS (20KB).  Phase 2: PV, lane owns f32x4 of h
// (8 x dwordx4 desc loads per 8-l iter), attn via uniform LDS broadcast.
// LDS 60.5KB -> 2 blocks/CU.  acc[5] f32x4 = 20 VGPR.
// ---------------------------------------------------------------------------
extern "C" __global__ __launch_bounds__(384)
void k4_out(const float* __restrict__ scores,
            const float* __restrict__ desc, float* __restrict__ out)
{
    __shared__ float scf[NS*NL];           // 40960 B
    __shared__ unsigned short at[NS*NL];   // 20480 B
    const int b = blockIdx.x, hh = blockIdx.y, t = threadIdx.x;

    // ---- load scores[b] -> LDS ----
    const float* sb = scores + (size_t)b*NS*NL;
    #pragma unroll 2
    for (int i4 = t; i4 < NS*NL/4; i4 += 384)
        *(f32x4*)&scf[4*i4] = *(const f32x4*)&sb[4*i4];
    __syncthreads();

    // ---- softmax: wave w does rows r = w + 6i; lane owns 8 l ----
    {
        const int w = t >> 6, L = t & 63;
        #pragma unroll
        for (int i = 0; i < 4; ++i) {
            const int r = w + 6*i;
            if (r < NS) {
                const f32x4 v0 = *(const f32x4*)&scf[r*NL + 8*L];
                const f32x4 v1 = *(const f32x4*)&scf[r*NL + 8*L + 4];
                float m = fmaxf(fmaxf(fmaxf(v0[0],v0[1]), fmaxf(v0[2],v0[3])),
                                fmaxf(fmaxf(v1[0],v1[1]), fmaxf(v1[2],v1[3])));
                #pragma unroll
                for (int off = 32; off; off >>= 1)
                    m = fmaxf(m, __shfl_xor(m, off));
                float e[8];
                #pragma unroll
                for (int c = 0; c < 4; ++c) { e[c] = __expf(v0[c]-m);
                                              e[4+c] = __expf(v1[c]-m); }
                float sum = ((e[0]+e[1])+(e[2]+e[3]))
                          + ((e[4]+e[5])+(e[6]+e[7]));
                #pragma unroll
                for (int off = 32; off; off >>= 1)
                    sum += __shfl_xor(sum, off);
                const float inv = 1.0f / sum;
                ushort8v o;
                #pragma unroll
                for (int c = 0; c < 8; ++c) o[c] = bf16_rne(e[c]*inv);
                *(ushort8v*)&at[r*NL + 8*L] = o;
            }
        }
    }
    __syncthreads();

    // ---- PV: xq = t%96 (f32x4 of h), sg = t/96 (5 s each) ----
    const int xq = t % 96, sg = t / 96;
    const float* db = desc + (size_t)b*NL*NH + hh*384 + 4*xq;
    f32x4 acc[5];
    #pragma unroll
    for (int i = 0; i < 5; ++i) acc[i] = (f32x4){0.f,0.f,0.f,0.f};

    #pragma unroll 2
    for (int l8 = 0; l8 < NL; l8 += 8) {
        f32x4 d[8];
        #pragma unroll
        for (int rr = 0; rr < 8; ++rr)
            d[rr] = *(const f32x4*)&db[(size_t)(l8 + rr)*NH];
        #pragma unroll
        for (int i = 0; i < 5; ++i) {
            const ushort8v pv = *(const ushort8v*)&at[(sg*5 + i)*NL + l8];
            #pragma unroll
            for (int rr = 0; rr < 8; ++rr) {
                const float p = bf16f(pv[rr]);
                acc[i][0] += p*d[rr][0]; acc[i][1] += p*d[rr][1];
                acc[i][2] += p*d[rr][2]; acc[i][3] += p*d[rr][3];
            }
        }
    }
    #pragma unroll
    for (int i = 0; i < 5; ++i)
        *(f32x4*)&out[(size_t)b*ROWE + (size_t)(sg*5 + i)*(ND+NH) + ND
                      + hh*384 + 4*xq] = acc[i];
}

// ---------------------------------------------------------------------------
extern "C" void kernel_launch(void* const* d_in, const int* in_sizes, int n_in,
                              void* d_out, int out_size, void* d_ws, size_t ws_size,
                              hipStream_t stream)
{
    const int*   skills = (const int*)  d_in[0];
    const float* desc   = (const float*)d_in[1];
    const float* embs   = (const float*)d_in[2];
    const float* W      = (const float*)d_in[3];
    float* out = (float*)d_out;

    unsigned short* qhi  = (unsigned short*)d_ws;          // [NB][NS][NH] bf16
    unsigned short* qlo  = qhi + (size_t)NB*NS*NH;         // [NB][NS][NH] bf16
    float* scores = (float*)(qlo + (size_t)NB*NS*NH);      // [NB][NS][NL] f32

    k1_q <<<NB,          256, 0, stream>>>(skills, embs, W, qhi, qlo, out);
    k2qk <<<dim3(NB, 2), 512, 0, stream>>>(qhi, qlo, desc, scores);
    k4_out<<<dim3(NB, 2), 384, 0, stream>>>(scores, desc, out);
}

// Round 12
// 256.770 us; speedup vs baseline: 2.2029x; 1.0268x over previous
//
#include <hip/hip_runtime.h>
#include <cstddef>
#include <cstdint>

#define NB 256
#define NS 20
#define NL 512
#define ND 128
#define NH 768
#define ROWE (NS*(ND+NH))   // 17920 floats per output row

typedef __attribute__((ext_vector_type(4))) float  f32x4;
typedef __attribute__((ext_vector_type(8))) short  bf16x8;
typedef __attribute__((ext_vector_type(4))) unsigned short ushort4v;
typedef __attribute__((ext_vector_type(8))) unsigned short ushort8v;

#define MFMA16 __builtin_amdgcn_mfma_f32_16x16x32_bf16

__device__ __forceinline__ unsigned short bf16_rne(float v){
    unsigned u = __builtin_bit_cast(unsigned, v);
    u = (u + 0x7fffu + ((u>>16)&1u)) >> 16;
    return (unsigned short)u;
}
__device__ __forceinline__ float bf16f(unsigned short h){
    unsigned u = ((unsigned)h)<<16;
    return __builtin_bit_cast(float, u);
}
// LDS-only barrier (no vmcnt drain): global prefetches stay in flight.
__device__ __forceinline__ void bar_lds(){
    asm volatile("s_waitcnt lgkmcnt(0)" ::: "memory");
    __builtin_amdgcn_s_barrier();
}

// ---------------------------------------------------------------------------
// K1: se = embs[skills[b]] -> out (concat left part);  q = se @ W -> bf16
// hi/lo arrays in ws. 256 blocks x 256 threads; wave w owns s in [5w,5w+5).
// ---------------------------------------------------------------------------
extern "C" __global__ __launch_bounds__(256)
void k1_q(const int* __restrict__ skills, const float* __restrict__ embs,
          const float* __restrict__ W,
          unsigned short* __restrict__ qhi, unsigned short* __restrict__ qlo,
          float* __restrict__ out)
{
    __shared__ float se[NS*ND];
    __shared__ int   sk[NS];
    const int b = blockIdx.x, t = threadIdx.x;
    if (t < NS) sk[t] = skills[b*NS + t];
    __syncthreads();
    for (int idx = t; idx < NS*ND; idx += 256) {
        const int s = idx >> 7, d = idx & (ND-1);
        const float v = embs[(size_t)sk[s]*ND + d];
        se[idx] = v;
        out[(size_t)b*ROWE + (size_t)s*(ND+NH) + d] = v;
    }
    __syncthreads();

    const int w = t >> 6, lane = t & 63;
    float acc[5][12];
    #pragma unroll
    for (int i = 0; i < 5; ++i)
        #pragma unroll
        for (int c = 0; c < 12; ++c) acc[i][c] = 0.f;

    const float* Wl = W + lane;
    for (int d4 = 0; d4 < ND/4; ++d4) {
        f32x4 sv[5];
        #pragma unroll
        for (int i = 0; i < 5; ++i)
            sv[i] = *(const f32x4*)&se[(5*w + i)*ND + 4*d4];
        #pragma unroll
        for (int r = 0; r < 4; ++r) {
            const float* wr = Wl + (size_t)(4*d4 + r)*NH;
            float wv[12];
            #pragma unroll
            for (int c = 0; c < 12; ++c) wv[c] = wr[64*c];
            #pragma unroll
            for (int i = 0; i < 5; ++i) {
                const float s_ = sv[i][r];
                #pragma unroll
                for (int c = 0; c < 12; ++c) acc[i][c] += s_*wv[c];
            }
        }
    }
    #pragma unroll
    for (int i = 0; i < 5; ++i)
        #pragma unroll
        for (int c = 0; c < 12; ++c) {
            const size_t idx = ((size_t)b*NS + 5*w + i)*NH + lane + 64*c;
            const float v = acc[i][c];
            const unsigned short hh = bf16_rne(v);
            qhi[idx] = hh;
            qlo[idx] = bf16_rne(v - bf16f(hh));
        }
}

// ---------------------------------------------------------------------------
// K2F: fused flash partial over an l-range of 256.  Grid (NB,2) split by l
// (row-disjoint desc -> desc crosses HBM exactly once; R11's h-split k4 was
// fetching desc twice via different XCD L2s).  512 threads (8 waves).
//
// Wave w: st = w&1 (QK s-tile), kq = w>>1 (QK k-quarter, 192 each).
// Per 16-row tile (16 tiles/block):
//   stage dt_hi/dt_lo [16][DTP] from sreg | B | QK MFMA (q from L2) + scr | B |
//   kq0: reduce + ONLINE softmax -> p_lds (bf16, unnorm) + f_lds (rescale) | B |
//   PV (VALU, all waves): thread (slot=t%96, sq=t/96<5) owns 8 h x 4 s;
//   one ds_read_b128 of dt_hi row per l (slot-strided, conflict-free);
//   acc[4][2x f32x4] rescaled by f then += p*v.  | B(top)
// Outputs UNNORMALIZED Opart + (m,sum) per (b,lh,s); k3_fin merges halves.
// No vt, no transpose, no second desc read.  LDS 56.5 KB -> 2 blocks/CU.
// ---------------------------------------------------------------------------
#define DTP 776

extern "C" __global__ __launch_bounds__(512)
void k2f(const unsigned short* __restrict__ qhi,
         const unsigned short* __restrict__ qlo,
         const float* __restrict__ desc,
         float* __restrict__ Opart, float* __restrict__ ms)
{
    __shared__ __align__(16) unsigned short dt_hi[16*DTP];   // 24832 B
    __shared__ __align__(16) unsigned short dt_lo[16*DTP];   // 24832 B
    __shared__ __align__(16) f32x4 scr[3][2][64];            // 6144 B
    __shared__ __align__(16) unsigned short p_lds[2][16][16];// 1024 B
    __shared__ float f_lds[2][16];                           // 128 B

    const int b = blockIdx.x, lh = blockIdx.y, t = threadIdx.x;
    const int w = t >> 6, L = t & 63;
    const int st = w & 1, kq = w >> 1;
    const int g = L >> 4, r16 = L & 15;
    const int slot = t % 96, sq = t / 96;    // PV mapping (sq==5 -> idle in PV)

    const float* dsrc = desc + ((size_t)b*NL + (size_t)lh*256)*NH;
    const int s_in = 16*st + r16;
    const size_t qrow = ((size_t)b*NS + (s_in < NS ? s_in : NS-1))*(size_t)NH;

    f32x4 acc4[4][2];
    #pragma unroll
    for (int j = 0; j < 4; ++j) {
        acc4[j][0] = (f32x4){0.f,0.f,0.f,0.f};
        acc4[j][1] = (f32x4){0.f,0.f,0.f,0.f};
    }
    float m_run = -1e30f, sum_run = 0.f;

    // staging regs: 6 f32x4/thread = 16x768 f32 tile (1-deep prefetch)
    f32x4 sreg[6];
    #pragma unroll
    for (int i = 0; i < 6; ++i)
        sreg[i] = *(const f32x4*)(dsrc + (size_t)4*(t + 512*i));

    #pragma unroll 1
    for (int tt = 0; tt < 16; ++tt) {
        bar_lds();   // B0: prior tile's PV done reading dt_hi

        // ---- stage dt: f32 regs -> bf16 hi/lo row-major ----
        #pragma unroll
        for (int i = 0; i < 6; ++i) {
            const int v = t + 512*i;
            const int l = v/192, h = 4*(v%192);
            ushort4v hi4, lo4;
            #pragma unroll
            for (int c = 0; c < 4; ++c) {
                const float x = sreg[i][c];
                const unsigned short hh = bf16_rne(x);
                hi4[c] = hh;
                lo4[c] = bf16_rne(x - bf16f(hh));
            }
            *(ushort4v*)&dt_hi[l*DTP + h] = hi4;
            *(ushort4v*)&dt_lo[l*DTP + h] = lo4;
        }
        // issue next tile's loads (in flight across QK+softmax+PV)
        if (tt < 15) {
            const float* nsrc = dsrc + (size_t)(tt+1)*16*NH;
            #pragma unroll
            for (int i = 0; i < 6; ++i)
                sreg[i] = *(const f32x4*)(nsrc + (size_t)4*(t + 512*i));
        }
        bar_lds();   // B1: dt ready

        // ---- QK^T partial: k in [192kq,192kq+192), q from global (L2) ----
        f32x4 Se = (f32x4){0.f,0.f,0.f,0.f};
        #pragma unroll
        for (int kb = 0; kb < 6; ++kb) {
            const int k0 = 192*kq + 32*kb;
            const bf16x8 Bh = *(const bf16x8*)&qhi[qrow + k0 + 8*g];
            const bf16x8 Bl = *(const bf16x8*)&qlo[qrow + k0 + 8*g];
            const bf16x8 Ah = *(const bf16x8*)&dt_hi[r16*DTP + k0 + 8*g];
            const bf16x8 Al = *(const bf16x8*)&dt_lo[r16*DTP + k0 + 8*g];
            Se = MFMA16(Ah, Bh, Se, 0,0,0);
            Se = MFMA16(Al, Bh, Se, 0,0,0);
            Se = MFMA16(Ah, Bl, Se, 0,0,0);
        }
        if (kq > 0) scr[kq-1][st][L] = Se;
        bar_lds();   // B2: partials ready

        // ---- kq==0 waves: reduce + online softmax ----
        if (kq == 0) {
            Se += scr[0][st][L];
            Se += scr[1][st][L];
            Se += scr[2][st][L];
            // lane holds S[l = 4g+r][s = 16st + r16]
            float pm = fmaxf(fmaxf(Se[0],Se[1]), fmaxf(Se[2],Se[3]));
            pm = fmaxf(pm, __shfl_xor(pm, 16));
            pm = fmaxf(pm, __shfl_xor(pm, 32));
            const float mnew = fmaxf(m_run, pm);
            const float fsc  = __expf(m_run - mnew);
            float pe[4];
            #pragma unroll
            for (int r = 0; r < 4; ++r) pe[r] = __expf(Se[r] - mnew);
            float ts = (pe[0]+pe[1]) + (pe[2]+pe[3]);
            ts += __shfl_xor(ts, 16);
            ts += __shfl_xor(ts, 32);
            sum_run = sum_run*fsc + ts;
            m_run = mnew;
            ushort4v pev;
            #pragma unroll
            for (int r = 0; r < 4; ++r) pev[r] = bf16_rne(pe[r]);
            *(ushort4v*)&p_lds[st][r16][4*g] = pev;   // [s&15][l=4g+r]
            if (L < 16) f_lds[st][L] = fsc;
        }
        bar_lds();   // B3: p_lds/f_lds ready

        // ---- PV (VALU): thread (slot, sq<5) owns h=8*slot..+7, s=4*sq+j ----
        if (sq < 5) {
            #pragma unroll
            for (int j = 0; j < 4; ++j) {
                const int s = 4*sq + j;
                const float f = f_lds[s>>4][s&15];
                acc4[j][0] *= f;  acc4[j][1] *= f;
            }
            ushort8v prA[4], prB[4];
            #pragma unroll
            for (int j = 0; j < 4; ++j) {
                const int s = 4*sq + j;
                prA[j] = *(const ushort8v*)&p_lds[s>>4][s&15][0];
                prB[j] = *(const ushort8v*)&p_lds[s>>4][s&15][8];
            }
            #pragma unroll
            for (int l = 0; l < 16; ++l) {
                const ushort8v dv = *(const ushort8v*)&dt_hi[l*DTP + 8*slot];
                f32x4 d0, d1;
                #pragma unroll
                for (int c = 0; c < 4; ++c) {
                    d0[c] = bf16f(dv[c]);
                    d1[c] = bf16f(dv[4+c]);
                }
                #pragma unroll
                for (int j = 0; j < 4; ++j) {
                    const unsigned short pu = (l < 8) ? prA[j][l] : prB[j][l-8];
                    const float p = bf16f(pu);
                    acc4[j][0] += p * d0;
                    acc4[j][1] += p * d1;
                }
            }
        }
    }

    // ---- epilogue: write 1/sum, then store unnormalized-rescaled partials --
    bar_lds();
    if (kq == 0 && L < 16) f_lds[st][L] = 1.0f / sum_run;
    bar_lds();
    if (sq < 5) {
        #pragma unroll
        for (int j = 0; j < 4; ++j) {
            const int s = 4*sq + j;
            const float inv = f_lds[s>>4][s&15];
            float* Ob = Opart + ((size_t)(b*2 + lh)*NS + s)*NH + 8*slot;
            f32x4 o0 = acc4[j][0], o1 = acc4[j][1];
            o0 *= inv;  o1 *= inv;
            *(f32x4*)&Ob[0] = o0;
            *(f32x4*)&Ob[4] = o1;
        }
    }
    if (kq == 0 && L < 16) {
        const int s2 = 16*st + L;
        if (s2 < NS) {
            ms[((size_t)(b*2 + lh)*NS + s2)*2 + 0] = m_run;
            ms[((size_t)(b*2 + lh)*NS + s2)*2 + 1] = sum_run;
        }
    }
}

// ---------------------------------------------------------------------------
// K3: merge the two l-half partials per (b,s).  Each half's O is normalized
// by its own sum; recombine with softmax-of-(m,sum) weights:
//   out = c0*O0 + c1*O1,  c_i = e^{m_i-m} s_i / (e^{m0-m}s0 + e^{m1-m}s1)
// ---------------------------------------------------------------------------
extern "C" __global__ __launch_bounds__(256)
void k3_fin(const float* __restrict__ Opart, const float* __restrict__ ms,
            float* __restrict__ out)
{
    __shared__ float c0s[NS], c1s[NS];
    const int b = blockIdx.x, t = threadIdx.x;
    if (t < NS) {
        const float m0 = ms[((size_t)(b*2 + 0)*NS + t)*2 + 0];
        const float s0 = ms[((size_t)(b*2 + 0)*NS + t)*2 + 1];
        const float m1 = ms[((size_t)(b*2 + 1)*NS + t)*2 + 0];
        const float s1 = ms[((size_t)(b*2 + 1)*NS + t)*2 + 1];
        const float m  = fmaxf(m0, m1);
        const float w0 = __expf(m0 - m)*s0, w1 = __expf(m1 - m)*s1;
        const float inv = 1.0f / (w0 + w1);
        c0s[t] = w0*inv;
        c1s[t] = w1*inv;
    }
    __syncthreads();
    const float* O0 = Opart + (size_t)(b*2 + 0)*NS*NH;
    const float* O1 = Opart + (size_t)(b*2 + 1)*NS*NH;
    #pragma unroll 1
    for (int i4 = t; i4 < NS*NH/4; i4 += 256) {
        const int idx = 4*i4;
        const int s = idx / NH, h = idx - s*NH;
        const f32x4 a = *(const f32x4*)&O0[idx];
        const f32x4 c = *(const f32x4*)&O1[idx];
        const float c0 = c0s[s], c1 = c1s[s];
        f32x4 o;
        o[0] = c0*a[0] + c1*c[0]; o[1] = c0*a[1] + c1*c[1];
        o[2] = c0*a[2] + c1*c[2]; o[3] = c0*a[3] + c1*c[3];
        *(f32x4*)&out[(size_t)b*ROWE + (size_t)s*(ND+NH) + ND + h] = o;
    }
}

// ---------------------------------------------------------------------------
extern "C" void kernel_launch(void* const* d_in, const int* in_sizes, int n_in,
                              void* d_out, int out_size, void* d_ws, size_t ws_size,
                              hipStream_t stream)
{
    const int*   skills = (const int*)  d_in[0];
    const float* desc   = (const float*)d_in[1];
    const float* embs   = (const float*)d_in[2];
    const float* W      = (const float*)d_in[3];
    float* out = (float*)d_out;

    unsigned short* qhi = (unsigned short*)d_ws;          // [NB][NS][NH] bf16
    unsigned short* qlo = qhi + (size_t)NB*NS*NH;         // [NB][NS][NH] bf16
    float* Opart = (float*)(qlo + (size_t)NB*NS*NH);      // [NB*2][NS][NH] f32
    float* ms    = Opart + (size_t)NB*2*NS*NH;            // [NB*2][NS][2]  f32

    k1_q  <<<NB,          256, 0, stream>>>(skills, embs, W, qhi, qlo, out);
    k2f   <<<dim3(NB, 2), 512, 0, stream>>>(qhi, qlo, desc, Opart, ms);
    k3_fin<<<NB,          256, 0, stream>>>(Opart, ms, out);
}

// Round 14
// 202.611 us; speedup vs baseline: 2.7918x; 1.2673x over previous
//
#include <hip/hip_runtime.h>
#include <cstddef>
#include <cstdint>

#define NB 256
#define NS 20
#define NL 512
#define ND 128
#define NH 768
#define ROWE (NS*(ND+NH))   // 17920 floats per output row

typedef __attribute__((ext_vector_type(4))) float  f32x4;
typedef __attribute__((ext_vector_type(8))) short  bf16x8;
typedef __attribute__((ext_vector_type(4))) unsigned short ushort4v;
typedef __attribute__((ext_vector_type(8))) unsigned short ushort8v;

#define MFMA16 __builtin_amdgcn_mfma_f32_16x16x32_bf16

__device__ __forceinline__ unsigned short bf16_rne(float v){
    unsigned u = __builtin_bit_cast(unsigned, v);
    u = (u + 0x7fffu + ((u>>16)&1u)) >> 16;
    return (unsigned short)u;
}
__device__ __forceinline__ float bf16f(unsigned short h){
    unsigned u = ((unsigned)h)<<16;
    return __builtin_bit_cast(float, u);
}
// LDS-only barrier (no vmcnt drain): global prefetches stay in flight.
__device__ __forceinline__ void bar_lds(){
    asm volatile("s_waitcnt lgkmcnt(0)" ::: "memory");
    __builtin_amdgcn_s_barrier();
}

// ---------------------------------------------------------------------------
// K1: se = embs[skills[b]] -> out (concat left part);  q = se @ W -> bf16
// hi/lo arrays in ws. 256 blocks x 256 threads; wave w owns s in [5w,5w+5).
// ---------------------------------------------------------------------------
extern "C" __global__ __launch_bounds__(256)
void k1_q(const int* __restrict__ skills, const float* __restrict__ embs,
          const float* __restrict__ W,
          unsigned short* __restrict__ qhi, unsigned short* __restrict__ qlo,
          float* __restrict__ out)
{
    __shared__ float se[NS*ND];
    __shared__ int   sk[NS];
    const int b = blockIdx.x, t = threadIdx.x;
    if (t < NS) sk[t] = skills[b*NS + t];
    __syncthreads();
    for (int idx = t; idx < NS*ND; idx += 256) {
        const int s = idx >> 7, d = idx & (ND-1);
        const float v = embs[(size_t)sk[s]*ND + d];
        se[idx] = v;
        out[(size_t)b*ROWE + (size_t)s*(ND+NH) + d] = v;
    }
    __syncthreads();

    const int w = t >> 6, lane = t & 63;
    float acc[5][12];
    #pragma unroll
    for (int i = 0; i < 5; ++i)
        #pragma unroll
        for (int c = 0; c < 12; ++c) acc[i][c] = 0.f;

    const float* Wl = W + lane;
    for (int d4 = 0; d4 < ND/4; ++d4) {
        f32x4 sv[5];
        #pragma unroll
        for (int i = 0; i < 5; ++i)
            sv[i] = *(const f32x4*)&se[(5*w + i)*ND + 4*d4];
        #pragma unroll
        for (int r = 0; r < 4; ++r) {
            const float* wr = Wl + (size_t)(4*d4 + r)*NH;
            float wv[12];
            #pragma unroll
            for (int c = 0; c < 12; ++c) wv[c] = wr[64*c];
            #pragma unroll
            for (int i = 0; i < 5; ++i) {
                const float s_ = sv[i][r];
                #pragma unroll
                for (int c = 0; c < 12; ++c) acc[i][c] += s_*wv[c];
            }
        }
    }
    #pragma unroll
    for (int i = 0; i < 5; ++i)
        #pragma unroll
        for (int c = 0; c < 12; ++c) {
            const size_t idx = ((size_t)b*NS + 5*w + i)*NH + lane + 64*c;
            const float v = acc[i][c];
            const unsigned short hh = bf16_rne(v);
            qhi[idx] = hh;
            qlo[idx] = bf16_rne(v - bf16f(hh));
        }
}

// ---------------------------------------------------------------------------
// K2F: fused flash partial over an l-range of 256.  Grid (NB,2) split by l.
// 512 threads (8 waves); wave w: st = w&1 (QK s-tile), kq = w>>1 (k-quarter).
//
// q hi/lo HOISTED to registers once per kernel (48 VGPR) — in-loop q reloads
// were ~240 MB/dispatch of HBM re-fetch (L2 evicted by the desc stream).
// No sreg prefetch (loads at tile top; co-resident block covers latency);
// PV reads p per-l from p_lds2 (no reg preload).  R14 fix vs R13: clamp
// lanes (s_in >= NS, st=1 r16>=4) must NOT write p_lds2 — their transposed-
// layout writes went out of bounds and corrupted the next l-row's P.
//
// Per 16-row tile (16/block):
//   [issue 6 f32x4 loads] B0 | stage dt_hi/dt_lo | B1 | QK MFMA (q in regs)
//   + scr | B2 | kq0: reduce + online softmax -> p_lds2/f_lds | B3 |
//   PV (VALU): thread (slot=t%96, sq=t/96<5) owns 8h x 4s; ds_read_b128 of
//   dt_hi row per l; p via b64 from p_lds2[l][4sq].
// Outputs UNNORMALIZED Opart + (m,sum); k3_fin merges the lh halves.
// LDS 56.7 KB -> 2 blocks/CU.
// ---------------------------------------------------------------------------
#define DTP 776

extern "C" __global__ __launch_bounds__(512)
void k2f(const unsigned short* __restrict__ qhi,
         const unsigned short* __restrict__ qlo,
         const float* __restrict__ desc,
         float* __restrict__ Opart, float* __restrict__ ms)
{
    __shared__ __align__(16) unsigned short dt_hi[16*DTP];    // 24832 B
    __shared__ __align__(16) unsigned short dt_lo[16*DTP];    // 24832 B
    __shared__ __align__(16) f32x4 scr[3][2][64];             // 6144 B
    __shared__ __align__(16) unsigned short p_lds2[16][24];   // 768 B
    __shared__ float f_lds[2][16];                            // 128 B

    const int b = blockIdx.x, lh = blockIdx.y, t = threadIdx.x;
    const int w = t >> 6, L = t & 63;
    const int st = w & 1, kq = w >> 1;
    const int g = L >> 4, r16 = L & 15;
    const int slot = t % 96, sq = t / 96;    // PV mapping (sq==5 idle in PV)

    const float* dsrc = desc + ((size_t)b*NL + (size_t)lh*256)*NH;
    const int s_in = 16*st + r16;
    const size_t qrow = ((size_t)b*NS + (s_in < NS ? s_in : NS-1))*(size_t)NH;

    // ---- hoist q (hi/lo) for this wave's k-quarter into registers ----
    bf16x8 qhreg[6], qlreg[6];
    #pragma unroll
    for (int kb = 0; kb < 6; ++kb) {
        const int k0 = 192*kq + 32*kb + 8*g;
        qhreg[kb] = *(const bf16x8*)&qhi[qrow + k0];
        qlreg[kb] = *(const bf16x8*)&qlo[qrow + k0];
    }

    f32x4 acc4[4][2];
    #pragma unroll
    for (int j = 0; j < 4; ++j) {
        acc4[j][0] = (f32x4){0.f,0.f,0.f,0.f};
        acc4[j][1] = (f32x4){0.f,0.f,0.f,0.f};
    }
    float m_run = -1e30f, sum_run = 0.f;

    #pragma unroll 1
    for (int tt = 0; tt < 16; ++tt) {
        // issue this tile's 6 loads (global; regs only, LDS untouched)
        f32x4 tmp[6];
        {
            const float* tsrc = dsrc + (size_t)tt*16*NH;
            #pragma unroll
            for (int i = 0; i < 6; ++i)
                tmp[i] = *(const f32x4*)(tsrc + (size_t)4*(t + 512*i));
        }
        bar_lds();   // B0: prior tile's PV done reading dt_hi

        // ---- stage dt: f32 -> bf16 hi/lo row-major ----
        #pragma unroll
        for (int i = 0; i < 6; ++i) {
            const int v = t + 512*i;
            const int l = v/192, h = 4*(v%192);
            ushort4v hi4, lo4;
            #pragma unroll
            for (int c = 0; c < 4; ++c) {
                const float x = tmp[i][c];
                const unsigned short hh = bf16_rne(x);
                hi4[c] = hh;
                lo4[c] = bf16_rne(x - bf16f(hh));
            }
            *(ushort4v*)&dt_hi[l*DTP + h] = hi4;
            *(ushort4v*)&dt_lo[l*DTP + h] = lo4;
        }
        bar_lds();   // B1: dt ready

        // ---- QK^T partial: k in [192kq,192kq+192), q in registers ----
        f32x4 Se = (f32x4){0.f,0.f,0.f,0.f};
        #pragma unroll
        for (int kb = 0; kb < 6; ++kb) {
            const int k0 = 192*kq + 32*kb;
            const bf16x8 Ah = *(const bf16x8*)&dt_hi[r16*DTP + k0 + 8*g];
            const bf16x8 Al = *(const bf16x8*)&dt_lo[r16*DTP + k0 + 8*g];
            Se = MFMA16(Ah, qhreg[kb], Se, 0,0,0);
            Se = MFMA16(Al, qhreg[kb], Se, 0,0,0);
            Se = MFMA16(Ah, qlreg[kb], Se, 0,0,0);
        }
        if (kq > 0) scr[kq-1][st][L] = Se;
        bar_lds();   // B2: partials ready

        // ---- kq==0 waves: reduce + online softmax ----
        if (kq == 0) {
            Se += scr[0][st][L];
            Se += scr[1][st][L];
            Se += scr[2][st][L];
            // lane holds S[l = 4g+r][s = 16st + r16]
            float pm = fmaxf(fmaxf(Se[0],Se[1]), fmaxf(Se[2],Se[3]));
            pm = fmaxf(pm, __shfl_xor(pm, 16));
            pm = fmaxf(pm, __shfl_xor(pm, 32));
            const float mnew = fmaxf(m_run, pm);
            const float fsc  = __expf(m_run - mnew);
            float pe[4];
            #pragma unroll
            for (int r = 0; r < 4; ++r) pe[r] = __expf(Se[r] - mnew);
            float ts = (pe[0]+pe[1]) + (pe[2]+pe[3]);
            ts += __shfl_xor(ts, 16);
            ts += __shfl_xor(ts, 32);
            sum_run = sum_run*fsc + ts;
            m_run = mnew;
            if (s_in < NS) {           // R14 FIX: clamp lanes must not write
                #pragma unroll
                for (int r = 0; r < 4; ++r)
                    p_lds2[4*g + r][s_in] = bf16_rne(pe[r]);
            }
            if (L < 16) f_lds[st][L] = fsc;
        }
        bar_lds();   // B3: p_lds2/f_lds ready

        // ---- PV (VALU): thread (slot, sq<5): h = 8*slot..+7, s = 4*sq+j ----
        if (sq < 5) {
            #pragma unroll
            for (int j = 0; j < 4; ++j) {
                const int s = 4*sq + j;
                const float f = f_lds[s>>4][s&15];
                acc4[j][0] *= f;  acc4[j][1] *= f;
            }
            #pragma unroll
            for (int l = 0; l < 16; ++l) {
                const ushort8v dv = *(const ushort8v*)&dt_hi[l*DTP + 8*slot];
                const ushort4v pv = *(const ushort4v*)&p_lds2[l][4*sq];
                f32x4 d0, d1;
                #pragma unroll
                for (int c = 0; c < 4; ++c) {
                    d0[c] = bf16f(dv[c]);
                    d1[c] = bf16f(dv[4+c]);
                }
                #pragma unroll
                for (int j = 0; j < 4; ++j) {
                    const float p = bf16f(pv[j]);
                    acc4[j][0] += p * d0;
                    acc4[j][1] += p * d1;
                }
            }
        }
    }

    // ---- epilogue: write 1/sum, then store per-half-normalized partials ----
    bar_lds();
    if (kq == 0 && L < 16) f_lds[st][L] = 1.0f / sum_run;
    bar_lds();
    if (sq < 5) {
        #pragma unroll
        for (int j = 0; j < 4; ++j) {
            const int s = 4*sq + j;
            const float inv = f_lds[s>>4][s&15];
            float* Ob = Opart + ((size_t)(b*2 + lh)*NS + s)*NH + 8*slot;
            f32x4 o0 = acc4[j][0], o1 = acc4[j][1];
            o0 *= inv;  o1 *= inv;
            *(f32x4*)&Ob[0] = o0;
            *(f32x4*)&Ob[4] = o1;
        }
    }
    if (kq == 0 && L < 16) {
        const int s2 = 16*st + L;
        if (s2 < NS) {
            ms[((size_t)(b*2 + lh)*NS + s2)*2 + 0] = m_run;
            ms[((size_t)(b*2 + lh)*NS + s2)*2 + 1] = sum_run;
        }
    }
}

// ---------------------------------------------------------------------------
// K3: merge the two l-half partials per (b,s).  Each half's O is normalized
// by its own sum; recombine with softmax-of-(m,sum) weights:
//   out = c0*O0 + c1*O1,  c_i = e^{m_i-m} s_i / (e^{m0-m}s0 + e^{m1-m}s1)
// ---------------------------------------------------------------------------
extern "C" __global__ __launch_bounds__(256)
void k3_fin(const float* __restrict__ Opart, const float* __restrict__ ms,
            float* __restrict__ out)
{
    __shared__ float c0s[NS], c1s[NS];
    const int b = blockIdx.x, t = threadIdx.x;
    if (t < NS) {
        const float m0 = ms[((size_t)(b*2 + 0)*NS + t)*2 + 0];
        const float s0 = ms[((size_t)(b*2 + 0)*NS + t)*2 + 1];
        const float m1 = ms[((size_t)(b*2 + 1)*NS + t)*2 + 0];
        const float s1 = ms[((size_t)(b*2 + 1)*NS + t)*2 + 1];
        const float m  = fmaxf(m0, m1);
        const float w0 = __expf(m0 - m)*s0, w1 = __expf(m1 - m)*s1;
        const float inv = 1.0f / (w0 + w1);
        c0s[t] = w0*inv;
        c1s[t] = w1*inv;
    }
    __syncthreads();
    const float* O0 = Opart + (size_t)(b*2 + 0)*NS*NH;
    const float* O1 = Opart + (size_t)(b*2 + 1)*NS*NH;
    #pragma unroll 1
    for (int i4 = t; i4 < NS*NH/4; i4 += 256) {
        const int idx = 4*i4;
        const int s = idx / NH, h = idx - s*NH;
        const f32x4 a = *(const f32x4*)&O0[idx];
        const f32x4 c = *(const f32x4*)&O1[idx];
        const float c0 = c0s[s], c1 = c1s[s];
        f32x4 o;
        o[0] = c0*a[0] + c1*c[0]; o[1] = c0*a[1] + c1*c[1];
        o[2] = c0*a[2] + c1*c[2]; o[3] = c0*a[3] + c1*c[3];
        *(f32x4*)&out[(size_t)b*ROWE + (size_t)s*(ND+NH) + ND + h] = o;
    }
}

// ---------------------------------------------------------------------------
extern "C" void kernel_launch(void* const* d_in, const int* in_sizes, int n_in,
                              void* d_out, int out_size, void* d_ws, size_t ws_size,
                              hipStream_t stream)
{
    const int*   skills = (const int*)  d_in[0];
    const float* desc   = (const float*)d_in[1];
    const float* embs   = (const float*)d_in[2];
    const float* W      = (const float*)d_in[3];
    float* out = (float*)d_out;

    unsigned short* qhi = (unsigned short*)d_ws;          // [NB][NS][NH] bf16
    unsigned short* qlo = qhi + (size_t)NB*NS*NH;         // [NB][NS][NH] bf16
    float* Opart = (float*)(qlo + (size_t)NB*NS*NH);      // [NB*2][NS][NH] f32
    float* ms    = Opart + (size_t)NB*2*NS*NH;            // [NB*2][NS][2]  f32

    k1_q  <<<NB,          256, 0, stream>>>(skills, embs, W, qhi, qlo, out);
    k2f   <<<dim3(NB, 2), 512, 0, stream>>>(qhi, qlo, desc, Opart, ms);
    k3_fin<<<NB,          256, 0, stream>>>(Opart, ms, out);
}

// Round 15
// 183.350 us; speedup vs baseline: 3.0851x; 1.1051x over previous
//
#include <hip/hip_runtime.h>
#include <cstddef>
#include <cstdint>

#define NB 256
#define NS 20
#define NL 512
#define ND 128
#define NH 768
#define ROWE (NS*(ND+NH))   // 17920 floats per output row

typedef __attribute__((ext_vector_type(4))) float  f32x4;
typedef __attribute__((ext_vector_type(8))) short  bf16x8;
typedef __attribute__((ext_vector_type(4))) unsigned short ushort4v;
typedef __attribute__((ext_vector_type(8))) unsigned short ushort8v;
typedef __attribute__((ext_vector_type(4))) unsigned int  uint4v;
typedef __attribute__((ext_vector_type(2))) unsigned int  uint2v;

#define MFMA16 __builtin_amdgcn_mfma_f32_16x16x32_bf16

__device__ __forceinline__ unsigned short bf16_rne(float v){
    unsigned u = __builtin_bit_cast(unsigned, v);
    u = (u + 0x7fffu + ((u>>16)&1u)) >> 16;
    return (unsigned short)u;
}
__device__ __forceinline__ float bf16f(unsigned short h){
    unsigned u = ((unsigned)h)<<16;
    return __builtin_bit_cast(float, u);
}
__device__ __forceinline__ float lo16f(unsigned u){
    return __builtin_bit_cast(float, u << 16);
}
__device__ __forceinline__ float hi16f(unsigned u){
    return __builtin_bit_cast(float, u & 0xffff0000u);
}
// LDS-only barrier (no vmcnt drain): global prefetches stay in flight.
__device__ __forceinline__ void bar_lds(){
    asm volatile("s_waitcnt lgkmcnt(0)" ::: "memory");
    __builtin_amdgcn_s_barrier();
}

// ---------------------------------------------------------------------------
// K1: se = embs[skills[b]] -> out (concat left part);  q = se @ W -> bf16
// hi/lo arrays in ws. 256 blocks x 256 threads; wave w owns s in [5w,5w+5).
// ---------------------------------------------------------------------------
extern "C" __global__ __launch_bounds__(256)
void k1_q(const int* __restrict__ skills, const float* __restrict__ embs,
          const float* __restrict__ W,
          unsigned short* __restrict__ qhi, unsigned short* __restrict__ qlo,
          float* __restrict__ out)
{
    __shared__ float se[NS*ND];
    __shared__ int   sk[NS];
    const int b = blockIdx.x, t = threadIdx.x;
    if (t < NS) sk[t] = skills[b*NS + t];
    __syncthreads();
    for (int idx = t; idx < NS*ND; idx += 256) {
        const int s = idx >> 7, d = idx & (ND-1);
        const float v = embs[(size_t)sk[s]*ND + d];
        se[idx] = v;
        out[(size_t)b*ROWE + (size_t)s*(ND+NH) + d] = v;
    }
    __syncthreads();

    const int w = t >> 6, lane = t & 63;
    float acc[5][12];
    #pragma unroll
    for (int i = 0; i < 5; ++i)
        #pragma unroll
        for (int c = 0; c < 12; ++c) acc[i][c] = 0.f;

    const float* Wl = W + lane;
    for (int d4 = 0; d4 < ND/4; ++d4) {
        f32x4 sv[5];
        #pragma unroll
        for (int i = 0; i < 5; ++i)
            sv[i] = *(const f32x4*)&se[(5*w + i)*ND + 4*d4];
        #pragma unroll
        for (int r = 0; r < 4; ++r) {
            const float* wr = Wl + (size_t)(4*d4 + r)*NH;
            float wv[12];
            #pragma unroll
            for (int c = 0; c < 12; ++c) wv[c] = wr[64*c];
            #pragma unroll
            for (int i = 0; i < 5; ++i) {
                const float s_ = sv[i][r];
                #pragma unroll
                for (int c = 0; c < 12; ++c) acc[i][c] += s_*wv[c];
            }
        }
    }
    #pragma unroll
    for (int i = 0; i < 5; ++i)
        #pragma unroll
        for (int c = 0; c < 12; ++c) {
            const size_t idx = ((size_t)b*NS + 5*w + i)*NH + lane + 64*c;
            const float v = acc[i][c];
            const unsigned short hh = bf16_rne(v);
            qhi[idx] = hh;
            qlo[idx] = bf16_rne(v - bf16f(hh));
        }
}

// ---------------------------------------------------------------------------
// K2F: fused flash partial over an l-range of 256.  Grid (NB,2) split by l.
// 512 threads (8 waves); wave w: st = w&1 (QK s-tile), kq = w>>1 (k-quarter).
//
// R15 = R14 + 1-deep register prefetch.  The only in-loop VMEM is the desc
// prefetch itself (q hoisted to 48 VGPR): stage(t) consumes loads issued one
// full tile ago (wait~0); loads(t+1) issued right after, in flight across
// QK+softmax+PV.  R12's failure mode (in-loop q loads forcing vmcnt(0) mid-
// tile, draining the prefetch queue) is structurally absent.
//
// Per 16-row tile (16/block):
//   B0 | stage dt_hi/dt_lo from sreg; issue sreg = loads(t+1) | B1 |
//   QK MFMA (q in regs) + scr | B2 | kq0: reduce + online softmax ->
//   p_lds2/f_lds | B3 | PV (VALU): thread (slot=t%96, sq=t/96<5) owns
//   8h x 4s; ds_read_b128 of dt_hi row per l; dword shift/mask bf16->f32.
// Outputs UNNORMALIZED Opart + (m,sum); k3_fin merges the lh halves.
// LDS 56.7 KB -> 2 blocks/CU (if VGPR <= 128).
// ---------------------------------------------------------------------------
#define DTP 776

extern "C" __global__ __launch_bounds__(512)
void k2f(const unsigned short* __restrict__ qhi,
         const unsigned short* __restrict__ qlo,
         const float* __restrict__ desc,
         float* __restrict__ Opart, float* __restrict__ ms)
{
    __shared__ __align__(16) unsigned short dt_hi[16*DTP];    // 24832 B
    __shared__ __align__(16) unsigned short dt_lo[16*DTP];    // 24832 B
    __shared__ __align__(16) f32x4 scr[3][2][64];             // 6144 B
    __shared__ __align__(16) unsigned short p_lds2[16][24];   // 768 B
    __shared__ float f_lds[2][16];                            // 128 B

    const int b = blockIdx.x, lh = blockIdx.y, t = threadIdx.x;
    const int w = t >> 6, L = t & 63;
    const int st = w & 1, kq = w >> 1;
    const int g = L >> 4, r16 = L & 15;
    const int slot = t % 96, sq = t / 96;    // PV mapping (sq==5 idle in PV)

    const float* dsrc = desc + ((size_t)b*NL + (size_t)lh*256)*NH;
    const int s_in = 16*st + r16;
    const size_t qrow = ((size_t)b*NS + (s_in < NS ? s_in : NS-1))*(size_t)NH;

    // ---- hoist q (hi/lo) for this wave's k-quarter into registers ----
    bf16x8 qhreg[6], qlreg[6];
    #pragma unroll
    for (int kb = 0; kb < 6; ++kb) {
        const int k0 = 192*kq + 32*kb + 8*g;
        qhreg[kb] = *(const bf16x8*)&qhi[qrow + k0];
        qlreg[kb] = *(const bf16x8*)&qlo[qrow + k0];
    }

    f32x4 acc4[4][2];
    #pragma unroll
    for (int j = 0; j < 4; ++j) {
        acc4[j][0] = (f32x4){0.f,0.f,0.f,0.f};
        acc4[j][1] = (f32x4){0.f,0.f,0.f,0.f};
    }
    float m_run = -1e30f, sum_run = 0.f;

    // ---- 1-deep prefetch pipeline: sreg holds tile tt's data at loop top --
    f32x4 sreg[6];
    #pragma unroll
    for (int i = 0; i < 6; ++i)
        sreg[i] = *(const f32x4*)(dsrc + (size_t)4*(t + 512*i));

    #pragma unroll 1
    for (int tt = 0; tt < 16; ++tt) {
        bar_lds();   // B0: prior tile's PV done reading dt_hi

        // ---- stage dt: f32 (in regs since last tile) -> bf16 hi/lo ----
        #pragma unroll
        for (int i = 0; i < 6; ++i) {
            const int v = t + 512*i;
            const int l = v/192, h = 4*(v%192);
            ushort4v hi4, lo4;
            #pragma unroll
            for (int c = 0; c < 4; ++c) {
                const float x = sreg[i][c];
                const unsigned short hh = bf16_rne(x);
                hi4[c] = hh;
                lo4[c] = bf16_rne(x - bf16f(hh));
            }
            *(ushort4v*)&dt_hi[l*DTP + h] = hi4;
            *(ushort4v*)&dt_lo[l*DTP + h] = lo4;
        }
        // ---- issue next tile's loads; in flight across QK+softmax+PV ----
        if (tt < 15) {
            const float* nsrc = dsrc + (size_t)(tt+1)*16*NH;
            #pragma unroll
            for (int i = 0; i < 6; ++i)
                sreg[i] = *(const f32x4*)(nsrc + (size_t)4*(t + 512*i));
        }
        bar_lds();   // B1: dt ready

        // ---- QK^T partial: k in [192kq,192kq+192), q in registers ----
        f32x4 Se = (f32x4){0.f,0.f,0.f,0.f};
        #pragma unroll
        for (int kb = 0; kb < 6; ++kb) {
            const int k0 = 192*kq + 32*kb;
            const bf16x8 Ah = *(const bf16x8*)&dt_hi[r16*DTP + k0 + 8*g];
            const bf16x8 Al = *(const bf16x8*)&dt_lo[r16*DTP + k0 + 8*g];
            Se = MFMA16(Ah, qhreg[kb], Se, 0,0,0);
            Se = MFMA16(Al, qhreg[kb], Se, 0,0,0);
            Se = MFMA16(Ah, qlreg[kb], Se, 0,0,0);
        }
        if (kq > 0) scr[kq-1][st][L] = Se;
        bar_lds();   // B2: partials ready

        // ---- kq==0 waves: reduce + online softmax ----
        if (kq == 0) {
            Se += scr[0][st][L];
            Se += scr[1][st][L];
            Se += scr[2][st][L];
            // lane holds S[l = 4g+r][s = 16st + r16]
            float pm = fmaxf(fmaxf(Se[0],Se[1]), fmaxf(Se[2],Se[3]));
            pm = fmaxf(pm, __shfl_xor(pm, 16));
            pm = fmaxf(pm, __shfl_xor(pm, 32));
            const float mnew = fmaxf(m_run, pm);
            const float fsc  = __expf(m_run - mnew);
            float pe[4];
            #pragma unroll
            for (int r = 0; r < 4; ++r) pe[r] = __expf(Se[r] - mnew);
            float ts = (pe[0]+pe[1]) + (pe[2]+pe[3]);
            ts += __shfl_xor(ts, 16);
            ts += __shfl_xor(ts, 32);
            sum_run = sum_run*fsc + ts;
            m_run = mnew;
            if (s_in < NS) {           // clamp lanes must not write (R14 fix)
                #pragma unroll
                for (int r = 0; r < 4; ++r)
                    p_lds2[4*g + r][s_in] = bf16_rne(pe[r]);
            }
            if (L < 16) f_lds[st][L] = fsc;
        }
        bar_lds();   // B3: p_lds2/f_lds ready

        // ---- PV (VALU): thread (slot, sq<5): h = 8*slot..+7, s = 4*sq+j ----
        if (sq < 5) {
            #pragma unroll
            for (int j = 0; j < 4; ++j) {
                const int s = 4*sq + j;
                const float f = f_lds[s>>4][s&15];
                acc4[j][0] *= f;  acc4[j][1] *= f;
            }
            #pragma unroll
            for (int l = 0; l < 16; ++l) {
                const ushort8v dv = *(const ushort8v*)&dt_hi[l*DTP + 8*slot];
                const ushort4v pv = *(const ushort4v*)&p_lds2[l][4*sq];
                const uint4v dw = __builtin_bit_cast(uint4v, dv);
                const uint2v pw = __builtin_bit_cast(uint2v, pv);
                f32x4 d0, d1;
                d0[0] = lo16f(dw[0]); d0[1] = hi16f(dw[0]);
                d0[2] = lo16f(dw[1]); d0[3] = hi16f(dw[1]);
                d1[0] = lo16f(dw[2]); d1[1] = hi16f(dw[2]);
                d1[2] = lo16f(dw[3]); d1[3] = hi16f(dw[3]);
                const float p0 = lo16f(pw[0]), p1 = hi16f(pw[0]);
                const float p2 = lo16f(pw[1]), p3 = hi16f(pw[1]);
                acc4[0][0] += p0 * d0;  acc4[0][1] += p0 * d1;
                acc4[1][0] += p1 * d0;  acc4[1][1] += p1 * d1;
                acc4[2][0] += p2 * d0;  acc4[2][1] += p2 * d1;
                acc4[3][0] += p3 * d0;  acc4[3][1] += p3 * d1;
            }
        }
    }

    // ---- epilogue: write 1/sum, then store per-half-normalized partials ----
    bar_lds();
    if (kq == 0 && L < 16) f_lds[st][L] = 1.0f / sum_run;
    bar_lds();
    if (sq < 5) {
        #pragma unroll
        for (int j = 0; j < 4; ++j) {
            const int s = 4*sq + j;
            const float inv = f_lds[s>>4][s&15];
            float* Ob = Opart + ((size_t)(b*2 + lh)*NS + s)*NH + 8*slot;
            f32x4 o0 = acc4[j][0], o1 = acc4[j][1];
            o0 *= inv;  o1 *= inv;
            *(f32x4*)&Ob[0] = o0;
            *(f32x4*)&Ob[4] = o1;
        }
    }
    if (kq == 0 && L < 16) {
        const int s2 = 16*st + L;
        if (s2 < NS) {
            ms[((size_t)(b*2 + lh)*NS + s2)*2 + 0] = m_run;
            ms[((size_t)(b*2 + lh)*NS + s2)*2 + 1] = sum_run;
        }
    }
}

// ---------------------------------------------------------------------------
// K3: merge the two l-half partials per (b,s).  Each half's O is normalized
// by its own sum; recombine with softmax-of-(m,sum) weights:
//   out = c0*O0 + c1*O1,  c_i = e^{m_i-m} s_i / (e^{m0-m}s0 + e^{m1-m}s1)
// ---------------------------------------------------------------------------
extern "C" __global__ __launch_bounds__(256)
void k3_fin(const float* __restrict__ Opart, const float* __restrict__ ms,
            float* __restrict__ out)
{
    __shared__ float c0s[NS], c1s[NS];
    const int b = blockIdx.x, t = threadIdx.x;
    if (t < NS) {
        const float m0 = ms[((size_t)(b*2 + 0)*NS + t)*2 + 0];
        const float s0 = ms[((size_t)(b*2 + 0)*NS + t)*2 + 1];
        const float m1 = ms[((size_t)(b*2 + 1)*NS + t)*2 + 0];
        const float s1 = ms[((size_t)(b*2 + 1)*NS + t)*2 + 1];
        const float m  = fmaxf(m0, m1);
        const float w0 = __expf(m0 - m)*s0, w1 = __expf(m1 - m)*s1;
        const float inv = 1.0f / (w0 + w1);
        c0s[t] = w0*inv;
        c1s[t] = w1*inv;
    }
    __syncthreads();
    const float* O0 = Opart + (size_t)(b*2 + 0)*NS*NH;
    const float* O1 = Opart + (size_t)(b*2 + 1)*NS*NH;
    #pragma unroll 1
    for (int i4 = t; i4 < NS*NH/4; i4 += 256) {
        const int idx = 4*i4;
        const int s = idx / NH, h = idx - s*NH;
        const f32x4 a = *(const f32x4*)&O0[idx];
        const f32x4 c = *(const f32x4*)&O1[idx];
        const float c0 = c0s[s], c1 = c1s[s];
        f32x4 o;
        o[0] = c0*a[0] + c1*c[0]; o[1] = c0*a[1] + c1*c[1];
        o[2] = c0*a[2] + c1*c[2]; o[3] = c0*a[3] + c1*c[3];
        *(f32x4*)&out[(size_t)b*ROWE + (size_t)s*(ND+NH) + ND + h] = o;
    }
}

// ---------------------------------------------------------------------------
extern "C" void kernel_launch(void* const* d_in, const int* in_sizes, int n_in,
                              void* d_out, int out_size, void* d_ws, size_t ws_size,
                              hipStream_t stream)
{
    const int*   skills = (const int*)  d_in[0];
    const float* desc   = (const float*)d_in[1];
    const float* embs   = (const float*)d_in[2];
    const float* W      = (const float*)d_in[3];
    float* out = (float*)d_out;

    unsigned short* qhi = (unsigned short*)d_ws;          // [NB][NS][NH] bf16
    unsigned short* qlo = qhi + (size_t)NB*NS*NH;         // [NB][NS][NH] bf16
    float* Opart = (float*)(qlo + (size_t)NB*NS*NH);      // [NB*2][NS][NH] f32
    float* ms    = Opart + (size_t)NB*2*NS*NH;            // [NB*2][NS][2]  f32

    k1_q  <<<NB,          256, 0, stream>>>(skills, embs, W, qhi, qlo, out);
    k2f   <<<dim3(NB, 2), 512, 0, stream>>>(qhi, qlo, desc, Opart, ms);
    k3_fin<<<NB,          256, 0, stream>>>(Opart, ms, out);
}